// Round 1
// baseline (525.583 us; speedup 1.0000x reference)
//
#include <hip/hip_runtime.h>

// ---------------- degree / CSR build ----------------

__global__ void k_init_deg(int* __restrict__ deg, int n) {
  int i = blockIdx.x * blockDim.x + threadIdx.x;
  if (i < n) deg[i] = 1;  // self-loop
}

__global__ void k_count(const int* __restrict__ dst, int* __restrict__ deg, int e) {
  int i = blockIdx.x * blockDim.x + threadIdx.x;
  if (i < e) atomicAdd(&deg[dst[i]], 1);
}

__global__ void k_dinv(const int* __restrict__ deg, float* __restrict__ dinv, int n) {
  int i = blockIdx.x * blockDim.x + threadIdx.x;
  if (i < n) dinv[i] = rsqrtf((float)deg[i]);
}

__global__ void k_scan1(const int* __restrict__ deg, int* __restrict__ rp,
                        int* __restrict__ psum, int n) {
  __shared__ int s[256];
  int tid = threadIdx.x;
  int i = blockIdx.x * 256 + tid;
  int v = (i < n) ? deg[i] : 0;
  int x = v;
  s[tid] = x; __syncthreads();
  for (int off = 1; off < 256; off <<= 1) {
    int t = (tid >= off) ? s[tid - off] : 0;
    __syncthreads();
    x += t; s[tid] = x;
    __syncthreads();
  }
  if (i < n) rp[i] = x - v;                 // exclusive within block
  if (tid == 255) psum[blockIdx.x] = x;     // block total
}

__global__ void k_scan2(int* __restrict__ psum, int nb) {
  __shared__ int s[256];
  int tid = threadIdx.x;
  int v = (tid < nb) ? psum[tid] : 0;
  int x = v;
  s[tid] = x; __syncthreads();
  for (int off = 1; off < 256; off <<= 1) {
    int t = (tid >= off) ? s[tid - off] : 0;
    __syncthreads();
    x += t; s[tid] = x;
    __syncthreads();
  }
  if (tid < nb) psum[tid] = x - v;          // exclusive prefix of block sums
}

__global__ void k_scan3(int* __restrict__ rp, int* __restrict__ cursor,
                        const int* __restrict__ psum, int n, int total) {
  int i = blockIdx.x * blockDim.x + threadIdx.x;
  if (i < n) {
    int r = rp[i] + psum[i >> 8];
    rp[i] = r;
    cursor[i] = r;
  }
  if (i == 0) rp[n] = total;
}

__global__ void k_scatter(const int* __restrict__ src, const int* __restrict__ dst,
                          const float* __restrict__ dinv, int* __restrict__ cursor,
                          int2* __restrict__ csr, int e, int n) {
  int i = blockIdx.x * blockDim.x + threadIdx.x;
  if (i >= e + n) return;
  int s, d;
  if (i < e) { s = src[i]; d = dst[i]; }
  else       { s = d = i - e; }             // self-loop
  int pos = atomicAdd(&cursor[d], 1);
  float w = dinv[s] * dinv[d];
  csr[pos] = make_int2(s, __float_as_int(w));
}

// ---------------- aggregation (pull, CSR by dst) ----------------

// width-7 aggregation on raw x: thread per (node, feature)
__global__ void k_agg7(const float* __restrict__ x, const int2* __restrict__ csr,
                       const int* __restrict__ rp, float* __restrict__ out, int n) {
  int t = blockIdx.x * blockDim.x + threadIdx.x;
  if (t >= n * 7) return;
  int v = t / 7, f = t - v * 7;
  int beg = rp[v], end = rp[v + 1];
  float acc = 0.f;
  for (int k = beg; k < end; ++k) {
    int2 e = csr[k];
    acc += __int_as_float(e.y) * x[(size_t)e.x * 7 + f];
  }
  out[(size_t)v * 7 + f] = acc;
}

// width-128 aggregation: wave per node, float2 per lane
__global__ void k_agg128(const float* __restrict__ t, const int2* __restrict__ csr,
                         const int* __restrict__ rp, float* __restrict__ out, int n) {
  int gid = blockIdx.x * blockDim.x + threadIdx.x;
  int v = gid >> 6, lane = gid & 63;
  if (v >= n) return;
  int beg = rp[v], end = rp[v + 1];
  float a0 = 0.f, a1 = 0.f;
  for (int k = beg; k < end; ++k) {
    int2 e = csr[k];
    float w = __int_as_float(e.y);
    float2 r = *(const float2*)(t + (size_t)e.x * 128 + 2 * lane);
    a0 += w * r.x;
    a1 += w * r.y;
  }
  float2* o = (float2*)(out + (size_t)v * 128);
  o[lane] = make_float2(a0, a1);
}

// width-64 aggregation + bias (final layer): wave per node
__global__ void k_agg64b(const float* __restrict__ t, const int2* __restrict__ csr,
                         const int* __restrict__ rp, const float* __restrict__ bias,
                         float* __restrict__ out, int n) {
  int gid = blockIdx.x * blockDim.x + threadIdx.x;
  int v = gid >> 6, lane = gid & 63;
  if (v >= n) return;
  int beg = rp[v], end = rp[v + 1];
  float a = 0.f;
  for (int k = beg; k < end; ++k) {
    int2 e = csr[k];
    a += __int_as_float(e.y) * t[(size_t)e.x * 64 + lane];
  }
  out[(size_t)v * 64 + lane] = a + bias[lane];
}

// ---------------- GEMMs (fp32, vector ALU) ----------------

// [n,7] @ [7,128] + b, relu. block = 2 rows x 128 cols
__global__ __launch_bounds__(256) void k_gemm1(const float* __restrict__ A,
                                               const float* __restrict__ W,
                                               const float* __restrict__ bias,
                                               float* __restrict__ out, int n) {
  __shared__ float ws[7 * 128];
  for (int j = threadIdx.x; j < 7 * 128; j += 256) ws[j] = W[j];
  __syncthreads();
  int r = blockIdx.x * 2 + (threadIdx.x >> 7);
  int c = threadIdx.x & 127;
  if (r >= n) return;
  const float* a = A + (size_t)r * 7;
  float acc = bias[c];
#pragma unroll
  for (int k = 0; k < 7; ++k) acc += a[k] * ws[k * 128 + c];
  out[(size_t)r * 128 + c] = fmaxf(acc, 0.f);
}

// [n,128] @ [128,128] + b, relu. W in LDS; wave = 4 rows, lane = cols (l, l+64)
__global__ __launch_bounds__(256) void k_gemm2(const float* __restrict__ H,
                                               const float* __restrict__ W,
                                               const float* __restrict__ bias,
                                               float* __restrict__ out, int n) {
  __shared__ float ws[128 * 128];
  {
    const float4* W4 = (const float4*)W;
    float4* S4 = (float4*)ws;
    for (int j = threadIdx.x; j < 128 * 128 / 4; j += 256) S4[j] = W4[j];
  }
  __syncthreads();
  int wave = threadIdx.x >> 6, lane = threadIdx.x & 63;
  int r0 = blockIdx.x * 16 + wave * 4;
  if (r0 >= n) return;
  int rr[4];
#pragma unroll
  for (int i = 0; i < 4; ++i) rr[i] = min(r0 + i, n - 1);
  float acc[4][2] = {};
  for (int k = 0; k < 128; k += 4) {
    float h[4][4];
#pragma unroll
    for (int i = 0; i < 4; ++i) {
      float4 t4 = *(const float4*)(H + (size_t)rr[i] * 128 + k);
      h[i][0] = t4.x; h[i][1] = t4.y; h[i][2] = t4.z; h[i][3] = t4.w;
    }
#pragma unroll
    for (int kk = 0; kk < 4; ++kk) {
      float w0 = ws[(k + kk) * 128 + lane];
      float w1 = ws[(k + kk) * 128 + lane + 64];
#pragma unroll
      for (int i = 0; i < 4; ++i) {
        acc[i][0] += h[i][kk] * w0;
        acc[i][1] += h[i][kk] * w1;
      }
    }
  }
  float b0 = bias[lane], b1 = bias[lane + 64];
#pragma unroll
  for (int i = 0; i < 4; ++i) {
    if (r0 + i < n) {
      out[(size_t)(r0 + i) * 128 + lane]      = fmaxf(acc[i][0] + b0, 0.f);
      out[(size_t)(r0 + i) * 128 + lane + 64] = fmaxf(acc[i][1] + b1, 0.f);
    }
  }
}

// [n,128] @ [128,64], no bias/relu. wave = 4 rows, lane = 1 col
__global__ __launch_bounds__(256) void k_gemm3(const float* __restrict__ H,
                                               const float* __restrict__ W,
                                               float* __restrict__ out, int n) {
  __shared__ float ws[128 * 64];
  {
    const float4* W4 = (const float4*)W;
    float4* S4 = (float4*)ws;
    for (int j = threadIdx.x; j < 128 * 64 / 4; j += 256) S4[j] = W4[j];
  }
  __syncthreads();
  int wave = threadIdx.x >> 6, lane = threadIdx.x & 63;
  int r0 = blockIdx.x * 16 + wave * 4;
  if (r0 >= n) return;
  int rr[4];
#pragma unroll
  for (int i = 0; i < 4; ++i) rr[i] = min(r0 + i, n - 1);
  float acc[4] = {};
  for (int k = 0; k < 128; k += 4) {
    float h[4][4];
#pragma unroll
    for (int i = 0; i < 4; ++i) {
      float4 t4 = *(const float4*)(H + (size_t)rr[i] * 128 + k);
      h[i][0] = t4.x; h[i][1] = t4.y; h[i][2] = t4.z; h[i][3] = t4.w;
    }
#pragma unroll
    for (int kk = 0; kk < 4; ++kk) {
      float w = ws[(k + kk) * 64 + lane];
#pragma unroll
      for (int i = 0; i < 4; ++i) acc[i] += h[i][kk] * w;
    }
  }
#pragma unroll
  for (int i = 0; i < 4; ++i)
    if (r0 + i < n) out[(size_t)(r0 + i) * 64 + lane] = acc[i];
}

// ---------------- mean pool over sorted batch ----------------

__global__ void k_pool(const float* __restrict__ h, const int* __restrict__ batch,
                       float* __restrict__ pooled, int n) {
  int g = blockIdx.x;
  // lower_bound(batch, g) and lower_bound(batch, g+1); batch is sorted
  int lo = 0, hi = n;
  while (lo < hi) { int m = (lo + hi) >> 1; if (batch[m] < g) lo = m + 1; else hi = m; }
  int start = lo;
  hi = n;
  while (lo < hi) { int m = (lo + hi) >> 1; if (batch[m] < g + 1) lo = m + 1; else hi = m; }
  int end = lo;

  int f = threadIdx.x & 63, j = threadIdx.x >> 6;
  float acc = 0.f;
  for (int i = start + j; i < end; i += 4) acc += h[(size_t)i * 64 + f];
  __shared__ float s[4][64];
  s[j][f] = acc;
  __syncthreads();
  if (threadIdx.x < 64) {
    float v = s[0][f] + s[1][f] + s[2][f] + s[3][f];
    float cnt = (float)(end - start);
    pooled[g * 64 + f] = v / fmaxf(cnt, 1.f);
  }
}

// ---------------- launch ----------------

extern "C" void kernel_launch(void* const* d_in, const int* in_sizes, int n_in,
                              void* d_out, int out_size, void* d_ws, size_t ws_size,
                              hipStream_t stream) {
  const float* x   = (const float*)d_in[0];
  const int* eidx  = (const int*)d_in[1];
  const int* batch = (const int*)d_in[2];
  const float* W1  = (const float*)d_in[3];
  const float* b1  = (const float*)d_in[4];
  const float* W2  = (const float*)d_in[5];
  const float* b2  = (const float*)d_in[6];
  const float* W3  = (const float*)d_in[7];
  const float* b3  = (const float*)d_in[8];
  float* out = (float*)d_out;

  const int n = in_sizes[0] / 7;       // 50000
  const int e = in_sizes[1] / 2;       // 800000
  const int G = out_size / 64 - n;     // 50
  const int m = e + n;                 // CSR entries incl self-loops

  // workspace carve-up (4B elements)
  float* wsf = (float*)d_ws;
  int*   wsi = (int*)d_ws;
  size_t off = 0;
  int*   deg    = wsi + off; off += n;
  float* dinv   = wsf + off; off += n;
  int*   rp     = wsi + off; off += (size_t)((n + 1 + 3) & ~3);
  int*   cursor = wsi + off; off += n;
  int*   psum   = wsi + off; off += 256;
  int2*  csr    = (int2*)(wsi + off); off += (size_t)2 * m;
  float* bufA   = wsf + off; off += (size_t)n * 128;
  float* bufB   = wsf + off; off += (size_t)n * 128;

  const int* src = eidx;       // edge_index[0]
  const int* dst = eidx + e;   // edge_index[1]

  const int nb = (n + 255) / 256;

  // CSR build
  k_init_deg<<<nb, 256, 0, stream>>>(deg, n);
  k_count<<<(e + 255) / 256, 256, 0, stream>>>(dst, deg, e);
  k_dinv<<<nb, 256, 0, stream>>>(deg, dinv, n);
  k_scan1<<<nb, 256, 0, stream>>>(deg, rp, psum, n);
  k_scan2<<<1, 256, 0, stream>>>(psum, nb);
  k_scan3<<<nb, 256, 0, stream>>>(rp, cursor, psum, n, m);
  k_scatter<<<(m + 255) / 256, 256, 0, stream>>>(src, dst, dinv, cursor, csr, e, n);

  // layer 1: AGG(x) [n,7] then @W1 + b1, relu  (AGG and linear commute)
  k_agg7<<<(n * 7 + 255) / 256, 256, 0, stream>>>(x, csr, rp, bufA, n);
  k_gemm1<<<(n + 1) / 2, 256, 0, stream>>>(bufA, W1, b1, bufB, n);

  // layer 2: AGG(h1) [n,128] then @W2 + b2, relu
  k_agg128<<<((size_t)n * 64 + 255) / 256, 256, 0, stream>>>(bufB, csr, rp, bufA, n);
  k_gemm2<<<(n + 15) / 16, 256, 0, stream>>>(bufA, W2, b2, bufB, n);

  // layer 3: h2 @ W3 [n,64] then AGG + b3 -> d_out
  k_gemm3<<<(n + 15) / 16, 256, 0, stream>>>(bufB, W3, bufA, n);
  k_agg64b<<<((size_t)n * 64 + 255) / 256, 256, 0, stream>>>(bufA, csr, rp, b3, out, n);

  // mean pool -> d_out tail
  k_pool<<<G, 256, 0, stream>>>(out, batch, out + (size_t)n * 64, n);
}

// Round 2
// 443.303 us; speedup vs baseline: 1.1856x; 1.1856x over previous
//
#include <hip/hip_runtime.h>

// ---------------- degree / CSR build ----------------

__global__ void k_init_deg(int* __restrict__ deg, int n) {
  int i = blockIdx.x * blockDim.x + threadIdx.x;
  if (i < n) deg[i] = 1;  // self-loop
}

__global__ void k_count(const int* __restrict__ dst, int* __restrict__ deg, int e) {
  int i = blockIdx.x * blockDim.x + threadIdx.x;
  if (i < e) atomicAdd(&deg[dst[i]], 1);
}

__global__ void k_dinv(const int* __restrict__ deg, float* __restrict__ dinv, int n) {
  int i = blockIdx.x * blockDim.x + threadIdx.x;
  if (i < n) dinv[i] = rsqrtf((float)deg[i]);
}

__global__ void k_scan1(const int* __restrict__ deg, int* __restrict__ rp,
                        int* __restrict__ psum, int n) {
  __shared__ int s[256];
  int tid = threadIdx.x;
  int i = blockIdx.x * 256 + tid;
  int v = (i < n) ? deg[i] : 0;
  int x = v;
  s[tid] = x; __syncthreads();
  for (int off = 1; off < 256; off <<= 1) {
    int t = (tid >= off) ? s[tid - off] : 0;
    __syncthreads();
    x += t; s[tid] = x;
    __syncthreads();
  }
  if (i < n) rp[i] = x - v;                 // exclusive within block
  if (tid == 255) psum[blockIdx.x] = x;     // block total
}

__global__ void k_scan2(int* __restrict__ psum, int nb) {
  __shared__ int s[256];
  int tid = threadIdx.x;
  int v = (tid < nb) ? psum[tid] : 0;
  int x = v;
  s[tid] = x; __syncthreads();
  for (int off = 1; off < 256; off <<= 1) {
    int t = (tid >= off) ? s[tid - off] : 0;
    __syncthreads();
    x += t; s[tid] = x;
    __syncthreads();
  }
  if (tid < nb) psum[tid] = x - v;          // exclusive prefix of block sums
}

__global__ void k_scan3(int* __restrict__ rp, int* __restrict__ cursor,
                        const int* __restrict__ psum, int n, int total) {
  int i = blockIdx.x * blockDim.x + threadIdx.x;
  if (i < n) {
    int r = rp[i] + psum[i >> 8];
    rp[i] = r;
    cursor[i] = r;
  }
  if (i == 0) rp[n] = total;
}

__global__ void k_scatter(const int* __restrict__ src, const int* __restrict__ dst,
                          const float* __restrict__ dinv, int* __restrict__ cursor,
                          int2* __restrict__ csr, int e, int n) {
  int i = blockIdx.x * blockDim.x + threadIdx.x;
  if (i >= e + n) return;
  int s, d;
  if (i < e) { s = src[i]; d = dst[i]; }
  else       { s = d = i - e; }             // self-loop
  int pos = atomicAdd(&cursor[d], 1);
  float w = dinv[s] * dinv[d];
  csr[pos] = make_int2(s, __float_as_int(w));
}

// ---------------- aggregation (pull, CSR by dst) ----------------
// All agg kernels: wave per node. CSR chunk (<=64 edges) preloaded
// lane-parallel (one coalesced load), broadcast via __shfl, gathers
// unrolled x4 so 4 independent loads are in flight per wave.

// width-7 aggregation on raw x: lane per edge + butterfly reduce
__global__ void k_agg7(const float* __restrict__ x, const int2* __restrict__ csr,
                       const int* __restrict__ rp, float* __restrict__ out, int n) {
  int gid = blockIdx.x * blockDim.x + threadIdx.x;
  int v = gid >> 6, lane = gid & 63;
  if (v >= n) return;
  int beg = rp[v], end = rp[v + 1];
  float a[7] = {0.f, 0.f, 0.f, 0.f, 0.f, 0.f, 0.f};
  for (int base = beg; base < end; base += 64) {
    int cnt = end - base; if (cnt > 64) cnt = 64;
    if (lane < cnt) {
      int2 e = csr[base + lane];
      float w = __int_as_float(e.y);
      const float* xr = x + (size_t)e.x * 7;
#pragma unroll
      for (int f = 0; f < 7; ++f) a[f] += w * xr[f];
    }
  }
#pragma unroll
  for (int off = 32; off > 0; off >>= 1) {
#pragma unroll
    for (int f = 0; f < 7; ++f) a[f] += __shfl_xor(a[f], off);
  }
  if (lane == 0) {
#pragma unroll
    for (int f = 0; f < 7; ++f) out[(size_t)v * 7 + f] = a[f];
  }
}

// width-128 aggregation: wave per node, float2 per lane
__global__ void k_agg128(const float* __restrict__ t, const int2* __restrict__ csr,
                         const int* __restrict__ rp, float* __restrict__ out, int n) {
  int gid = blockIdx.x * blockDim.x + threadIdx.x;
  int v = gid >> 6, lane = gid & 63;
  if (v >= n) return;
  int beg = rp[v], end = rp[v + 1];
  float a0 = 0.f, a1 = 0.f;
  const float* tp = t + 2 * lane;
  for (int base = beg; base < end; base += 64) {
    int cnt = end - base; if (cnt > 64) cnt = 64;
    int2 e = csr[base + (lane < cnt ? lane : cnt - 1)];
    int j = 0;
    for (; j + 4 <= cnt; j += 4) {
      int s0 = __shfl(e.x, j + 0), s1 = __shfl(e.x, j + 1);
      int s2 = __shfl(e.x, j + 2), s3 = __shfl(e.x, j + 3);
      int w0 = __shfl(e.y, j + 0), w1 = __shfl(e.y, j + 1);
      int w2 = __shfl(e.y, j + 2), w3 = __shfl(e.y, j + 3);
      float2 r0 = *(const float2*)(tp + (size_t)s0 * 128);
      float2 r1 = *(const float2*)(tp + (size_t)s1 * 128);
      float2 r2 = *(const float2*)(tp + (size_t)s2 * 128);
      float2 r3 = *(const float2*)(tp + (size_t)s3 * 128);
      a0 += __int_as_float(w0) * r0.x; a1 += __int_as_float(w0) * r0.y;
      a0 += __int_as_float(w1) * r1.x; a1 += __int_as_float(w1) * r1.y;
      a0 += __int_as_float(w2) * r2.x; a1 += __int_as_float(w2) * r2.y;
      a0 += __int_as_float(w3) * r3.x; a1 += __int_as_float(w3) * r3.y;
    }
    for (; j < cnt; ++j) {
      int s0 = __shfl(e.x, j);
      float w0 = __int_as_float(__shfl(e.y, j));
      float2 r0 = *(const float2*)(tp + (size_t)s0 * 128);
      a0 += w0 * r0.x; a1 += w0 * r0.y;
    }
  }
  *(float2*)(out + (size_t)v * 128 + 2 * lane) = make_float2(a0, a1);
}

// width-64 aggregation + bias (final layer): wave per node
__global__ void k_agg64b(const float* __restrict__ t, const int2* __restrict__ csr,
                         const int* __restrict__ rp, const float* __restrict__ bias,
                         float* __restrict__ out, int n) {
  int gid = blockIdx.x * blockDim.x + threadIdx.x;
  int v = gid >> 6, lane = gid & 63;
  if (v >= n) return;
  int beg = rp[v], end = rp[v + 1];
  float a = 0.f;
  const float* tp = t + lane;
  for (int base = beg; base < end; base += 64) {
    int cnt = end - base; if (cnt > 64) cnt = 64;
    int2 e = csr[base + (lane < cnt ? lane : cnt - 1)];
    int j = 0;
    for (; j + 4 <= cnt; j += 4) {
      int s0 = __shfl(e.x, j + 0), s1 = __shfl(e.x, j + 1);
      int s2 = __shfl(e.x, j + 2), s3 = __shfl(e.x, j + 3);
      int w0 = __shfl(e.y, j + 0), w1 = __shfl(e.y, j + 1);
      int w2 = __shfl(e.y, j + 2), w3 = __shfl(e.y, j + 3);
      float r0 = tp[(size_t)s0 * 64];
      float r1 = tp[(size_t)s1 * 64];
      float r2 = tp[(size_t)s2 * 64];
      float r3 = tp[(size_t)s3 * 64];
      a += __int_as_float(w0) * r0;
      a += __int_as_float(w1) * r1;
      a += __int_as_float(w2) * r2;
      a += __int_as_float(w3) * r3;
    }
    for (; j < cnt; ++j) {
      int s0 = __shfl(e.x, j);
      float w0 = __int_as_float(__shfl(e.y, j));
      a += w0 * tp[(size_t)s0 * 64];
    }
  }
  out[(size_t)v * 64 + lane] = a + bias[lane];
}

// ---------------- GEMMs (fp32, vector ALU) ----------------

// [n,7] @ [7,128] + b, relu. block = 2 rows x 128 cols
__global__ __launch_bounds__(256) void k_gemm1(const float* __restrict__ A,
                                               const float* __restrict__ W,
                                               const float* __restrict__ bias,
                                               float* __restrict__ out, int n) {
  __shared__ float ws[7 * 128];
  for (int j = threadIdx.x; j < 7 * 128; j += 256) ws[j] = W[j];
  __syncthreads();
  int r = blockIdx.x * 2 + (threadIdx.x >> 7);
  int c = threadIdx.x & 127;
  if (r >= n) return;
  const float* a = A + (size_t)r * 7;
  float acc = bias[c];
#pragma unroll
  for (int k = 0; k < 7; ++k) acc += a[k] * ws[k * 128 + c];
  out[(size_t)r * 128 + c] = fmaxf(acc, 0.f);
}

// [n,128] @ [128,128] + b, relu. W in LDS; wave = 8 rows, lane = cols (l, l+64)
__global__ __launch_bounds__(256) void k_gemm2(const float* __restrict__ H,
                                               const float* __restrict__ W,
                                               const float* __restrict__ bias,
                                               float* __restrict__ out, int n) {
  __shared__ float ws[128 * 128];
  {
    const float4* W4 = (const float4*)W;
    float4* S4 = (float4*)ws;
    for (int j = threadIdx.x; j < 128 * 128 / 4; j += 256) S4[j] = W4[j];
  }
  __syncthreads();
  int wave = threadIdx.x >> 6, lane = threadIdx.x & 63;
  int r0 = blockIdx.x * 32 + wave * 8;
  if (r0 >= n) return;
  int rr[8];
#pragma unroll
  for (int i = 0; i < 8; ++i) rr[i] = min(r0 + i, n - 1);
  float acc[8][2] = {};
  for (int k = 0; k < 128; k += 4) {
    float h[8][4];
#pragma unroll
    for (int i = 0; i < 8; ++i) {
      float4 t4 = *(const float4*)(H + (size_t)rr[i] * 128 + k);
      h[i][0] = t4.x; h[i][1] = t4.y; h[i][2] = t4.z; h[i][3] = t4.w;
    }
#pragma unroll
    for (int kk = 0; kk < 4; ++kk) {
      float w0 = ws[(k + kk) * 128 + lane];
      float w1 = ws[(k + kk) * 128 + lane + 64];
#pragma unroll
      for (int i = 0; i < 8; ++i) {
        acc[i][0] += h[i][kk] * w0;
        acc[i][1] += h[i][kk] * w1;
      }
    }
  }
  float b0 = bias[lane], b1 = bias[lane + 64];
#pragma unroll
  for (int i = 0; i < 8; ++i) {
    if (r0 + i < n) {
      out[(size_t)(r0 + i) * 128 + lane]      = fmaxf(acc[i][0] + b0, 0.f);
      out[(size_t)(r0 + i) * 128 + lane + 64] = fmaxf(acc[i][1] + b1, 0.f);
    }
  }
}

// [n,128] @ [128,64], no bias/relu. wave = 8 rows, lane = 1 col
__global__ __launch_bounds__(256) void k_gemm3(const float* __restrict__ H,
                                               const float* __restrict__ W,
                                               float* __restrict__ out, int n) {
  __shared__ float ws[128 * 64];
  {
    const float4* W4 = (const float4*)W;
    float4* S4 = (float4*)ws;
    for (int j = threadIdx.x; j < 128 * 64 / 4; j += 256) S4[j] = W4[j];
  }
  __syncthreads();
  int wave = threadIdx.x >> 6, lane = threadIdx.x & 63;
  int r0 = blockIdx.x * 32 + wave * 8;
  if (r0 >= n) return;
  int rr[8];
#pragma unroll
  for (int i = 0; i < 8; ++i) rr[i] = min(r0 + i, n - 1);
  float acc[8] = {};
  for (int k = 0; k < 128; k += 4) {
    float h[8][4];
#pragma unroll
    for (int i = 0; i < 8; ++i) {
      float4 t4 = *(const float4*)(H + (size_t)rr[i] * 128 + k);
      h[i][0] = t4.x; h[i][1] = t4.y; h[i][2] = t4.z; h[i][3] = t4.w;
    }
#pragma unroll
    for (int kk = 0; kk < 4; ++kk) {
      float w = ws[(k + kk) * 64 + lane];
#pragma unroll
      for (int i = 0; i < 8; ++i) acc[i] += h[i][kk] * w;
    }
  }
#pragma unroll
  for (int i = 0; i < 8; ++i)
    if (r0 + i < n) out[(size_t)(r0 + i) * 64 + lane] = acc[i];
}

// ---------------- mean pool over sorted batch ----------------

__global__ void k_pool(const float* __restrict__ h, const int* __restrict__ batch,
                       float* __restrict__ pooled, int n) {
  int g = blockIdx.x;
  int lo = 0, hi = n;
  while (lo < hi) { int m = (lo + hi) >> 1; if (batch[m] < g) lo = m + 1; else hi = m; }
  int start = lo;
  hi = n;
  while (lo < hi) { int m = (lo + hi) >> 1; if (batch[m] < g + 1) lo = m + 1; else hi = m; }
  int end = lo;

  int f = threadIdx.x & 63, j = threadIdx.x >> 6;
  float acc = 0.f;
  for (int i = start + j; i < end; i += 4) acc += h[(size_t)i * 64 + f];
  __shared__ float s[4][64];
  s[j][f] = acc;
  __syncthreads();
  if (threadIdx.x < 64) {
    float v = s[0][f] + s[1][f] + s[2][f] + s[3][f];
    float cnt = (float)(end - start);
    pooled[g * 64 + f] = v / fmaxf(cnt, 1.f);
  }
}

// ---------------- launch ----------------

extern "C" void kernel_launch(void* const* d_in, const int* in_sizes, int n_in,
                              void* d_out, int out_size, void* d_ws, size_t ws_size,
                              hipStream_t stream) {
  const float* x   = (const float*)d_in[0];
  const int* eidx  = (const int*)d_in[1];
  const int* batch = (const int*)d_in[2];
  const float* W1  = (const float*)d_in[3];
  const float* b1  = (const float*)d_in[4];
  const float* W2  = (const float*)d_in[5];
  const float* b2  = (const float*)d_in[6];
  const float* W3  = (const float*)d_in[7];
  const float* b3  = (const float*)d_in[8];
  float* out = (float*)d_out;

  const int n = in_sizes[0] / 7;       // 50000
  const int e = in_sizes[1] / 2;       // 800000
  const int G = out_size / 64 - n;     // 50
  const int m = e + n;                 // CSR entries incl self-loops

  // workspace carve-up (4B elements)
  float* wsf = (float*)d_ws;
  int*   wsi = (int*)d_ws;
  size_t off = 0;
  int*   deg    = wsi + off; off += n;
  float* dinv   = wsf + off; off += n;
  int*   rp     = wsi + off; off += (size_t)((n + 1 + 3) & ~3);
  int*   cursor = wsi + off; off += n;
  int*   psum   = wsi + off; off += 256;
  int2*  csr    = (int2*)(wsi + off); off += (size_t)2 * m;
  float* bufA   = wsf + off; off += (size_t)n * 128;
  float* bufB   = wsf + off; off += (size_t)n * 128;

  const int* src = eidx;       // edge_index[0]
  const int* dst = eidx + e;   // edge_index[1]

  const int nb = (n + 255) / 256;

  // CSR build
  k_init_deg<<<nb, 256, 0, stream>>>(deg, n);
  k_count<<<(e + 255) / 256, 256, 0, stream>>>(dst, deg, e);
  k_dinv<<<nb, 256, 0, stream>>>(deg, dinv, n);
  k_scan1<<<nb, 256, 0, stream>>>(deg, rp, psum, n);
  k_scan2<<<1, 256, 0, stream>>>(psum, nb);
  k_scan3<<<nb, 256, 0, stream>>>(rp, cursor, psum, n, m);
  k_scatter<<<(m + 255) / 256, 256, 0, stream>>>(src, dst, dinv, cursor, csr, e, n);

  // layer 1: AGG(x) [n,7] then @W1 + b1, relu  (AGG and linear commute)
  k_agg7<<<((size_t)n * 64 + 255) / 256, 256, 0, stream>>>(x, csr, rp, bufA, n);
  k_gemm1<<<(n + 1) / 2, 256, 0, stream>>>(bufA, W1, b1, bufB, n);

  // layer 2: AGG(h1) [n,128] then @W2 + b2, relu
  k_agg128<<<((size_t)n * 64 + 255) / 256, 256, 0, stream>>>(bufB, csr, rp, bufA, n);
  k_gemm2<<<(n + 31) / 32, 256, 0, stream>>>(bufA, W2, b2, bufB, n);

  // layer 3: h2 @ W3 [n,64] then AGG + b3 -> d_out
  k_gemm3<<<(n + 31) / 32, 256, 0, stream>>>(bufB, W3, bufA, n);
  k_agg64b<<<((size_t)n * 64 + 255) / 256, 256, 0, stream>>>(bufA, csr, rp, b3, out, n);

  // mean pool -> d_out tail
  k_pool<<<G, 256, 0, stream>>>(out, batch, out + (size_t)n * 64, n);
}

// Round 3
// 431.928 us; speedup vs baseline: 1.2168x; 1.0263x over previous
//
#include <hip/hip_runtime.h>

// ---------------- degree / CSR build ----------------

__global__ void k_init_deg(int* __restrict__ deg, int n) {
  int i = blockIdx.x * blockDim.x + threadIdx.x;
  if (i < n) deg[i] = 1;  // self-loop
}

__global__ void k_count(const int* __restrict__ dst, int* __restrict__ deg, int e) {
  int i = blockIdx.x * blockDim.x + threadIdx.x;
  if (i < e) atomicAdd(&deg[dst[i]], 1);
}

__global__ void k_dinv(const int* __restrict__ deg, float* __restrict__ dinv, int n) {
  int i = blockIdx.x * blockDim.x + threadIdx.x;
  if (i < n) dinv[i] = rsqrtf((float)deg[i]);
}

__global__ void k_scan1(const int* __restrict__ deg, int* __restrict__ rp,
                        int* __restrict__ psum, int n) {
  __shared__ int s[256];
  int tid = threadIdx.x;
  int i = blockIdx.x * 256 + tid;
  int v = (i < n) ? deg[i] : 0;
  int x = v;
  s[tid] = x; __syncthreads();
  for (int off = 1; off < 256; off <<= 1) {
    int t = (tid >= off) ? s[tid - off] : 0;
    __syncthreads();
    x += t; s[tid] = x;
    __syncthreads();
  }
  if (i < n) rp[i] = x - v;                 // exclusive within block
  if (tid == 255) psum[blockIdx.x] = x;     // block total
}

__global__ void k_scan2(int* __restrict__ psum, int nb) {
  __shared__ int s[256];
  int tid = threadIdx.x;
  int v = (tid < nb) ? psum[tid] : 0;
  int x = v;
  s[tid] = x; __syncthreads();
  for (int off = 1; off < 256; off <<= 1) {
    int t = (tid >= off) ? s[tid - off] : 0;
    __syncthreads();
    x += t; s[tid] = x;
    __syncthreads();
  }
  if (tid < nb) psum[tid] = x - v;          // exclusive prefix of block sums
}

__global__ void k_scan3(int* __restrict__ rp, int* __restrict__ cursor,
                        const int* __restrict__ psum, int n, int total) {
  int i = blockIdx.x * blockDim.x + threadIdx.x;
  if (i < n) {
    int r = rp[i] + psum[i >> 8];
    rp[i] = r;
    cursor[i] = r;
  }
  if (i == 0) rp[n] = total;
}

__global__ void k_scatter(const int* __restrict__ src, const int* __restrict__ dst,
                          const float* __restrict__ dinv, int* __restrict__ cursor,
                          int2* __restrict__ csr, int e, int n) {
  int i = blockIdx.x * blockDim.x + threadIdx.x;
  if (i >= e + n) return;
  int s, d;
  if (i < e) { s = src[i]; d = dst[i]; }
  else       { s = d = i - e; }             // self-loop
  int pos = atomicAdd(&cursor[d], 1);
  float w = dinv[s] * dinv[d];
  csr[pos] = make_int2(s, __float_as_int(w));
}

// ---------------- aggregation (pull, CSR by dst) ----------------

// width-7 aggregation on raw x: lane per edge + butterfly reduce
__global__ void k_agg7(const float* __restrict__ x, const int2* __restrict__ csr,
                       const int* __restrict__ rp, float* __restrict__ out, int n) {
  int gid = blockIdx.x * blockDim.x + threadIdx.x;
  int v = gid >> 6, lane = gid & 63;
  if (v >= n) return;
  int beg = rp[v], end = rp[v + 1];
  float a[7] = {0.f, 0.f, 0.f, 0.f, 0.f, 0.f, 0.f};
  for (int base = beg; base < end; base += 64) {
    int cnt = end - base; if (cnt > 64) cnt = 64;
    if (lane < cnt) {
      int2 e = csr[base + lane];
      float w = __int_as_float(e.y);
      const float* xr = x + (size_t)e.x * 7;
#pragma unroll
      for (int f = 0; f < 7; ++f) a[f] += w * xr[f];
    }
  }
#pragma unroll
  for (int off = 32; off > 0; off >>= 1) {
#pragma unroll
    for (int f = 0; f < 7; ++f) a[f] += __shfl_xor(a[f], off);
  }
  if (lane == 0) {
#pragma unroll
    for (int f = 0; f < 7; ++f) out[(size_t)v * 7 + f] = a[f];
  }
}

// width-128 aggregation: wave per node, float2 per lane
__global__ void k_agg128(const float* __restrict__ t, const int2* __restrict__ csr,
                         const int* __restrict__ rp, float* __restrict__ out, int n) {
  int gid = blockIdx.x * blockDim.x + threadIdx.x;
  int v = gid >> 6, lane = gid & 63;
  if (v >= n) return;
  int beg = rp[v], end = rp[v + 1];
  float a0 = 0.f, a1 = 0.f;
  const float* tp = t + 2 * lane;
  for (int base = beg; base < end; base += 64) {
    int cnt = end - base; if (cnt > 64) cnt = 64;
    int2 e = csr[base + (lane < cnt ? lane : cnt - 1)];
    int j = 0;
    for (; j + 4 <= cnt; j += 4) {
      int s0 = __shfl(e.x, j + 0), s1 = __shfl(e.x, j + 1);
      int s2 = __shfl(e.x, j + 2), s3 = __shfl(e.x, j + 3);
      int w0 = __shfl(e.y, j + 0), w1 = __shfl(e.y, j + 1);
      int w2 = __shfl(e.y, j + 2), w3 = __shfl(e.y, j + 3);
      float2 r0 = *(const float2*)(tp + (size_t)s0 * 128);
      float2 r1 = *(const float2*)(tp + (size_t)s1 * 128);
      float2 r2 = *(const float2*)(tp + (size_t)s2 * 128);
      float2 r3 = *(const float2*)(tp + (size_t)s3 * 128);
      a0 += __int_as_float(w0) * r0.x; a1 += __int_as_float(w0) * r0.y;
      a0 += __int_as_float(w1) * r1.x; a1 += __int_as_float(w1) * r1.y;
      a0 += __int_as_float(w2) * r2.x; a1 += __int_as_float(w2) * r2.y;
      a0 += __int_as_float(w3) * r3.x; a1 += __int_as_float(w3) * r3.y;
    }
    for (; j < cnt; ++j) {
      int s0 = __shfl(e.x, j);
      float w0 = __int_as_float(__shfl(e.y, j));
      float2 r0 = *(const float2*)(tp + (size_t)s0 * 128);
      a0 += w0 * r0.x; a1 += w0 * r0.y;
    }
  }
  *(float2*)(out + (size_t)v * 128 + 2 * lane) = make_float2(a0, a1);
}

// width-64 aggregation + bias (final layer): wave per node
__global__ void k_agg64b(const float* __restrict__ t, const int2* __restrict__ csr,
                         const int* __restrict__ rp, const float* __restrict__ bias,
                         float* __restrict__ out, int n) {
  int gid = blockIdx.x * blockDim.x + threadIdx.x;
  int v = gid >> 6, lane = gid & 63;
  if (v >= n) return;
  int beg = rp[v], end = rp[v + 1];
  float a = 0.f;
  const float* tp = t + lane;
  for (int base = beg; base < end; base += 64) {
    int cnt = end - base; if (cnt > 64) cnt = 64;
    int2 e = csr[base + (lane < cnt ? lane : cnt - 1)];
    int j = 0;
    for (; j + 4 <= cnt; j += 4) {
      int s0 = __shfl(e.x, j + 0), s1 = __shfl(e.x, j + 1);
      int s2 = __shfl(e.x, j + 2), s3 = __shfl(e.x, j + 3);
      int w0 = __shfl(e.y, j + 0), w1 = __shfl(e.y, j + 1);
      int w2 = __shfl(e.y, j + 2), w3 = __shfl(e.y, j + 3);
      float r0 = tp[(size_t)s0 * 64];
      float r1 = tp[(size_t)s1 * 64];
      float r2 = tp[(size_t)s2 * 64];
      float r3 = tp[(size_t)s3 * 64];
      a += __int_as_float(w0) * r0;
      a += __int_as_float(w1) * r1;
      a += __int_as_float(w2) * r2;
      a += __int_as_float(w3) * r3;
    }
    for (; j < cnt; ++j) {
      int s0 = __shfl(e.x, j);
      float w0 = __int_as_float(__shfl(e.y, j));
      a += w0 * tp[(size_t)s0 * 64];
    }
  }
  out[(size_t)v * 64 + lane] = a + bias[lane];
}

// ---------------- GEMMs (fp32, vector ALU) ----------------

// [n,7] @ [7,128] + b, relu. block = 2 rows x 128 cols
__global__ __launch_bounds__(256) void k_gemm1(const float* __restrict__ A,
                                               const float* __restrict__ W,
                                               const float* __restrict__ bias,
                                               float* __restrict__ out, int n) {
  __shared__ float ws[7 * 128];
  for (int j = threadIdx.x; j < 7 * 128; j += 256) ws[j] = W[j];
  __syncthreads();
  int r = blockIdx.x * 2 + (threadIdx.x >> 7);
  int c = threadIdx.x & 127;
  if (r >= n) return;
  const float* a = A + (size_t)r * 7;
  float acc = bias[c];
#pragma unroll
  for (int k = 0; k < 7; ++k) acc += a[k] * ws[k * 128 + c];
  out[(size_t)r * 128 + c] = fmaxf(acc, 0.f);
}

// [n,128] @ [128,128] + b, relu.
// W staged in two 32KB k-halves (LDS 32KB -> 5 blocks/CU; occupancy cap
// moves to the 128-VGPR 16-waves/CU rule instead of LDS's 8).
// wave = 8 rows; lane owns adjacent cols (2l, 2l+1) -> ds_read_b64 + float2 store.
__global__ __launch_bounds__(256) void k_gemm2(const float* __restrict__ H,
                                               const float* __restrict__ W,
                                               const float* __restrict__ bias,
                                               float* __restrict__ out, int n) {
  __shared__ float ws[64 * 128];  // 32 KiB
  int wave = threadIdx.x >> 6, lane = threadIdx.x & 63;
  int r0 = blockIdx.x * 32 + wave * 8;
  int rr[8];
#pragma unroll
  for (int i = 0; i < 8; ++i) rr[i] = min(r0 + i, n - 1);
  float acc[8][2] = {};

#pragma unroll
  for (int half = 0; half < 2; ++half) {
    {
      const float4* W4 = (const float4*)(W + half * 64 * 128);
      float4* S4 = (float4*)ws;
      for (int j = threadIdx.x; j < 64 * 128 / 4; j += 256) S4[j] = W4[j];
    }
    __syncthreads();
    const float* Hh = H + half * 64;
    for (int k = 0; k < 64; k += 4) {
      float h[8][4];
#pragma unroll
      for (int i = 0; i < 8; ++i) {
        float4 t4 = *(const float4*)(Hh + (size_t)rr[i] * 128 + k);
        h[i][0] = t4.x; h[i][1] = t4.y; h[i][2] = t4.z; h[i][3] = t4.w;
      }
#pragma unroll
      for (int kk = 0; kk < 4; ++kk) {
        float2 w2 = *(const float2*)&ws[(k + kk) * 128 + 2 * lane];
#pragma unroll
        for (int i = 0; i < 8; ++i) {
          acc[i][0] += h[i][kk] * w2.x;
          acc[i][1] += h[i][kk] * w2.y;
        }
      }
    }
    __syncthreads();
  }

  float2 b2 = *(const float2*)&bias[2 * lane];
#pragma unroll
  for (int i = 0; i < 8; ++i) {
    if (r0 + i < n) {
      float2 o = make_float2(fmaxf(acc[i][0] + b2.x, 0.f),
                             fmaxf(acc[i][1] + b2.y, 0.f));
      *(float2*)(out + (size_t)(r0 + i) * 128 + 2 * lane) = o;
    }
  }
}

// [n,128] @ [128,64], no bias/relu. wave = 8 rows, lane = 1 col
__global__ __launch_bounds__(256) void k_gemm3(const float* __restrict__ H,
                                               const float* __restrict__ W,
                                               float* __restrict__ out, int n) {
  __shared__ float ws[128 * 64];
  {
    const float4* W4 = (const float4*)W;
    float4* S4 = (float4*)ws;
    for (int j = threadIdx.x; j < 128 * 64 / 4; j += 256) S4[j] = W4[j];
  }
  __syncthreads();
  int wave = threadIdx.x >> 6, lane = threadIdx.x & 63;
  int r0 = blockIdx.x * 32 + wave * 8;
  if (r0 >= n) return;
  int rr[8];
#pragma unroll
  for (int i = 0; i < 8; ++i) rr[i] = min(r0 + i, n - 1);
  float acc[8] = {};
  for (int k = 0; k < 128; k += 4) {
    float h[8][4];
#pragma unroll
    for (int i = 0; i < 8; ++i) {
      float4 t4 = *(const float4*)(H + (size_t)rr[i] * 128 + k);
      h[i][0] = t4.x; h[i][1] = t4.y; h[i][2] = t4.z; h[i][3] = t4.w;
    }
#pragma unroll
    for (int kk = 0; kk < 4; ++kk) {
      float w = ws[(k + kk) * 64 + lane];
#pragma unroll
      for (int i = 0; i < 8; ++i) acc[i] += h[i][kk] * w;
    }
  }
#pragma unroll
  for (int i = 0; i < 8; ++i)
    if (r0 + i < n) out[(size_t)(r0 + i) * 64 + lane] = acc[i];
}

// ---------------- mean pool over sorted batch ----------------

__global__ void k_pool(const float* __restrict__ h, const int* __restrict__ batch,
                       float* __restrict__ pooled, int n) {
  int g = blockIdx.x;
  int lo = 0, hi = n;
  while (lo < hi) { int m = (lo + hi) >> 1; if (batch[m] < g) lo = m + 1; else hi = m; }
  int start = lo;
  hi = n;
  while (lo < hi) { int m = (lo + hi) >> 1; if (batch[m] < g + 1) lo = m + 1; else hi = m; }
  int end = lo;

  int f = threadIdx.x & 63, j = threadIdx.x >> 6;
  float acc = 0.f;
  for (int i = start + j; i < end; i += 4) acc += h[(size_t)i * 64 + f];
  __shared__ float s[4][64];
  s[j][f] = acc;
  __syncthreads();
  if (threadIdx.x < 64) {
    float v = s[0][f] + s[1][f] + s[2][f] + s[3][f];
    float cnt = (float)(end - start);
    pooled[g * 64 + f] = v / fmaxf(cnt, 1.f);
  }
}

// ---------------- launch ----------------

extern "C" void kernel_launch(void* const* d_in, const int* in_sizes, int n_in,
                              void* d_out, int out_size, void* d_ws, size_t ws_size,
                              hipStream_t stream) {
  const float* x   = (const float*)d_in[0];
  const int* eidx  = (const int*)d_in[1];
  const int* batch = (const int*)d_in[2];
  const float* W1  = (const float*)d_in[3];
  const float* b1  = (const float*)d_in[4];
  const float* W2  = (const float*)d_in[5];
  const float* b2  = (const float*)d_in[6];
  const float* W3  = (const float*)d_in[7];
  const float* b3  = (const float*)d_in[8];
  float* out = (float*)d_out;

  const int n = in_sizes[0] / 7;       // 50000
  const int e = in_sizes[1] / 2;       // 800000
  const int G = out_size / 64 - n;     // 50
  const int m = e + n;                 // CSR entries incl self-loops

  // workspace carve-up (4B elements)
  float* wsf = (float*)d_ws;
  int*   wsi = (int*)d_ws;
  size_t off = 0;
  int*   deg    = wsi + off; off += n;
  float* dinv   = wsf + off; off += n;
  int*   rp     = wsi + off; off += (size_t)((n + 1 + 3) & ~3);
  int*   cursor = wsi + off; off += n;
  int*   psum   = wsi + off; off += 256;
  int2*  csr    = (int2*)(wsi + off); off += (size_t)2 * m;
  float* bufA   = wsf + off; off += (size_t)n * 128;
  float* bufB   = wsf + off; off += (size_t)n * 128;

  const int* src = eidx;       // edge_index[0]
  const int* dst = eidx + e;   // edge_index[1]

  const int nb = (n + 255) / 256;

  // CSR build
  k_init_deg<<<nb, 256, 0, stream>>>(deg, n);
  k_count<<<(e + 255) / 256, 256, 0, stream>>>(dst, deg, e);
  k_dinv<<<nb, 256, 0, stream>>>(deg, dinv, n);
  k_scan1<<<nb, 256, 0, stream>>>(deg, rp, psum, n);
  k_scan2<<<1, 256, 0, stream>>>(psum, nb);
  k_scan3<<<nb, 256, 0, stream>>>(rp, cursor, psum, n, m);
  k_scatter<<<(m + 255) / 256, 256, 0, stream>>>(src, dst, dinv, cursor, csr, e, n);

  // layer 1: AGG(x) [n,7] then @W1 + b1, relu  (AGG and linear commute)
  k_agg7<<<((size_t)n * 64 + 255) / 256, 256, 0, stream>>>(x, csr, rp, bufA, n);
  k_gemm1<<<(n + 1) / 2, 256, 0, stream>>>(bufA, W1, b1, bufB, n);

  // layer 2: AGG(h1) [n,128] then @W2 + b2, relu
  k_agg128<<<((size_t)n * 64 + 255) / 256, 256, 0, stream>>>(bufB, csr, rp, bufA, n);
  k_gemm2<<<(n + 31) / 32, 256, 0, stream>>>(bufA, W2, b2, bufB, n);

  // layer 3: h2 @ W3 [n,64] then AGG + b3 -> d_out
  k_gemm3<<<(n + 31) / 32, 256, 0, stream>>>(bufB, W3, bufA, n);
  k_agg64b<<<((size_t)n * 64 + 255) / 256, 256, 0, stream>>>(bufA, csr, rp, b3, out, n);

  // mean pool -> d_out tail
  k_pool<<<G, 256, 0, stream>>>(out, batch, out + (size_t)n * 64, n);
}

// Round 4
// 386.249 us; speedup vs baseline: 1.3607x; 1.1183x over previous
//
#include <hip/hip_runtime.h>

// ---------------- degree / CSR build ----------------

__global__ void k_init_deg(int* __restrict__ deg, int n) {
  int i = blockIdx.x * blockDim.x + threadIdx.x;
  if (i < n) deg[i] = 1;  // self-loop
}

__global__ void k_count(const int* __restrict__ dst, int* __restrict__ deg, int e) {
  int i = blockIdx.x * blockDim.x + threadIdx.x;
  if (i < e) atomicAdd(&deg[dst[i]], 1);
}

__global__ void k_dinv(const int* __restrict__ deg, float* __restrict__ dinv, int n) {
  int i = blockIdx.x * blockDim.x + threadIdx.x;
  if (i < n) dinv[i] = rsqrtf((float)deg[i]);
}

__global__ void k_scan1(const int* __restrict__ deg, int* __restrict__ rp,
                        int* __restrict__ psum, int n) {
  __shared__ int s[256];
  int tid = threadIdx.x;
  int i = blockIdx.x * 256 + tid;
  int v = (i < n) ? deg[i] : 0;
  int x = v;
  s[tid] = x; __syncthreads();
  for (int off = 1; off < 256; off <<= 1) {
    int t = (tid >= off) ? s[tid - off] : 0;
    __syncthreads();
    x += t; s[tid] = x;
    __syncthreads();
  }
  if (i < n) rp[i] = x - v;                 // exclusive within block
  if (tid == 255) psum[blockIdx.x] = x;     // block total
}

__global__ void k_scan2(int* __restrict__ psum, int nb) {
  __shared__ int s[256];
  int tid = threadIdx.x;
  int v = (tid < nb) ? psum[tid] : 0;
  int x = v;
  s[tid] = x; __syncthreads();
  for (int off = 1; off < 256; off <<= 1) {
    int t = (tid >= off) ? s[tid - off] : 0;
    __syncthreads();
    x += t; s[tid] = x;
    __syncthreads();
  }
  if (tid < nb) psum[tid] = x - v;          // exclusive prefix of block sums
}

__global__ void k_scan3(int* __restrict__ rp, int* __restrict__ cursor,
                        const int* __restrict__ psum, int n, int total) {
  int i = blockIdx.x * blockDim.x + threadIdx.x;
  if (i < n) {
    int r = rp[i] + psum[i >> 8];
    rp[i] = r;
    cursor[i] = r;
  }
  if (i == 0) rp[n] = total;
}

__global__ void k_scatter(const int* __restrict__ src, const int* __restrict__ dst,
                          const float* __restrict__ dinv, int* __restrict__ cursor,
                          int2* __restrict__ csr, int e, int n) {
  int i = blockIdx.x * blockDim.x + threadIdx.x;
  if (i >= e + n) return;
  int s, d;
  if (i < e) { s = src[i]; d = dst[i]; }
  else       { s = d = i - e; }             // self-loop
  int pos = atomicAdd(&cursor[d], 1);
  float w = dinv[s] * dinv[d];
  csr[pos] = make_int2(s, __float_as_int(w));
}

// ---------------- aggregation (pull, CSR by dst) ----------------

// width-7 aggregation on raw x: lane per edge + butterfly reduce
__global__ void k_agg7(const float* __restrict__ x, const int2* __restrict__ csr,
                       const int* __restrict__ rp, float* __restrict__ out, int n) {
  int gid = blockIdx.x * blockDim.x + threadIdx.x;
  int v = gid >> 6, lane = gid & 63;
  if (v >= n) return;
  int beg = rp[v], end = rp[v + 1];
  float a[7] = {0.f, 0.f, 0.f, 0.f, 0.f, 0.f, 0.f};
  for (int base = beg; base < end; base += 64) {
    int cnt = end - base; if (cnt > 64) cnt = 64;
    if (lane < cnt) {
      int2 e = csr[base + lane];
      float w = __int_as_float(e.y);
      const float* xr = x + (size_t)e.x * 7;
#pragma unroll
      for (int f = 0; f < 7; ++f) a[f] += w * xr[f];
    }
  }
#pragma unroll
  for (int off = 32; off > 0; off >>= 1) {
#pragma unroll
    for (int f = 0; f < 7; ++f) a[f] += __shfl_xor(a[f], off);
  }
  if (lane == 0) {
#pragma unroll
    for (int f = 0; f < 7; ++f) out[(size_t)v * 7 + f] = a[f];
  }
}

// width-128 aggregation: wave per node, float2 per lane
__global__ void k_agg128(const float* __restrict__ t, const int2* __restrict__ csr,
                         const int* __restrict__ rp, float* __restrict__ out, int n) {
  int gid = blockIdx.x * blockDim.x + threadIdx.x;
  int v = gid >> 6, lane = gid & 63;
  if (v >= n) return;
  int beg = rp[v], end = rp[v + 1];
  float a0 = 0.f, a1 = 0.f;
  const float* tp = t + 2 * lane;
  for (int base = beg; base < end; base += 64) {
    int cnt = end - base; if (cnt > 64) cnt = 64;
    int2 e = csr[base + (lane < cnt ? lane : cnt - 1)];
    int j = 0;
    for (; j + 4 <= cnt; j += 4) {
      int s0 = __shfl(e.x, j + 0), s1 = __shfl(e.x, j + 1);
      int s2 = __shfl(e.x, j + 2), s3 = __shfl(e.x, j + 3);
      int w0 = __shfl(e.y, j + 0), w1 = __shfl(e.y, j + 1);
      int w2 = __shfl(e.y, j + 2), w3 = __shfl(e.y, j + 3);
      float2 r0 = *(const float2*)(tp + (size_t)s0 * 128);
      float2 r1 = *(const float2*)(tp + (size_t)s1 * 128);
      float2 r2 = *(const float2*)(tp + (size_t)s2 * 128);
      float2 r3 = *(const float2*)(tp + (size_t)s3 * 128);
      a0 += __int_as_float(w0) * r0.x; a1 += __int_as_float(w0) * r0.y;
      a0 += __int_as_float(w1) * r1.x; a1 += __int_as_float(w1) * r1.y;
      a0 += __int_as_float(w2) * r2.x; a1 += __int_as_float(w2) * r2.y;
      a0 += __int_as_float(w3) * r3.x; a1 += __int_as_float(w3) * r3.y;
    }
    for (; j < cnt; ++j) {
      int s0 = __shfl(e.x, j);
      float w0 = __int_as_float(__shfl(e.y, j));
      float2 r0 = *(const float2*)(tp + (size_t)s0 * 128);
      a0 += w0 * r0.x; a1 += w0 * r0.y;
    }
  }
  *(float2*)(out + (size_t)v * 128 + 2 * lane) = make_float2(a0, a1);
}

// width-64 aggregation + bias (final layer): wave per node
__global__ void k_agg64b(const float* __restrict__ t, const int2* __restrict__ csr,
                         const int* __restrict__ rp, const float* __restrict__ bias,
                         float* __restrict__ out, int n) {
  int gid = blockIdx.x * blockDim.x + threadIdx.x;
  int v = gid >> 6, lane = gid & 63;
  if (v >= n) return;
  int beg = rp[v], end = rp[v + 1];
  float a = 0.f;
  const float* tp = t + lane;
  for (int base = beg; base < end; base += 64) {
    int cnt = end - base; if (cnt > 64) cnt = 64;
    int2 e = csr[base + (lane < cnt ? lane : cnt - 1)];
    int j = 0;
    for (; j + 4 <= cnt; j += 4) {
      int s0 = __shfl(e.x, j + 0), s1 = __shfl(e.x, j + 1);
      int s2 = __shfl(e.x, j + 2), s3 = __shfl(e.x, j + 3);
      int w0 = __shfl(e.y, j + 0), w1 = __shfl(e.y, j + 1);
      int w2 = __shfl(e.y, j + 2), w3 = __shfl(e.y, j + 3);
      float r0 = tp[(size_t)s0 * 64];
      float r1 = tp[(size_t)s1 * 64];
      float r2 = tp[(size_t)s2 * 64];
      float r3 = tp[(size_t)s3 * 64];
      a += __int_as_float(w0) * r0;
      a += __int_as_float(w1) * r1;
      a += __int_as_float(w2) * r2;
      a += __int_as_float(w3) * r3;
    }
    for (; j < cnt; ++j) {
      int s0 = __shfl(e.x, j);
      float w0 = __int_as_float(__shfl(e.y, j));
      a += w0 * tp[(size_t)s0 * 64];
    }
  }
  out[(size_t)v * 64 + lane] = a + bias[lane];
}

// ---------------- GEMMs (fp32, vector ALU) ----------------

// [n,7] @ [7,128] + b, relu. block = 2 rows x 128 cols
__global__ __launch_bounds__(256) void k_gemm1(const float* __restrict__ A,
                                               const float* __restrict__ W,
                                               const float* __restrict__ bias,
                                               float* __restrict__ out, int n) {
  __shared__ float ws[7 * 128];
  for (int j = threadIdx.x; j < 7 * 128; j += 256) ws[j] = W[j];
  __syncthreads();
  int r = blockIdx.x * 2 + (threadIdx.x >> 7);
  int c = threadIdx.x & 127;
  if (r >= n) return;
  const float* a = A + (size_t)r * 7;
  float acc = bias[c];
#pragma unroll
  for (int k = 0; k < 7; ++k) acc += a[k] * ws[k * 128 + c];
  out[(size_t)r * 128 + c] = fmaxf(acc, 0.f);
}

// [n,128] @ [128,128] + b, relu. W staged in two 32KB k-halves.
__global__ __launch_bounds__(256) void k_gemm2(const float* __restrict__ H,
                                               const float* __restrict__ W,
                                               const float* __restrict__ bias,
                                               float* __restrict__ out, int n) {
  __shared__ float ws[64 * 128];  // 32 KiB
  int wave = threadIdx.x >> 6, lane = threadIdx.x & 63;
  int r0 = blockIdx.x * 32 + wave * 8;
  int rr[8];
#pragma unroll
  for (int i = 0; i < 8; ++i) rr[i] = min(r0 + i, n - 1);
  float acc[8][2] = {};

#pragma unroll
  for (int half = 0; half < 2; ++half) {
    {
      const float4* W4 = (const float4*)(W + half * 64 * 128);
      float4* S4 = (float4*)ws;
      for (int j = threadIdx.x; j < 64 * 128 / 4; j += 256) S4[j] = W4[j];
    }
    __syncthreads();
    const float* Hh = H + half * 64;
    for (int k = 0; k < 64; k += 4) {
      float h[8][4];
#pragma unroll
      for (int i = 0; i < 8; ++i) {
        float4 t4 = *(const float4*)(Hh + (size_t)rr[i] * 128 + k);
        h[i][0] = t4.x; h[i][1] = t4.y; h[i][2] = t4.z; h[i][3] = t4.w;
      }
#pragma unroll
      for (int kk = 0; kk < 4; ++kk) {
        float2 w2 = *(const float2*)&ws[(k + kk) * 128 + 2 * lane];
#pragma unroll
        for (int i = 0; i < 8; ++i) {
          acc[i][0] += h[i][kk] * w2.x;
          acc[i][1] += h[i][kk] * w2.y;
        }
      }
    }
    __syncthreads();
  }

  float2 b2 = *(const float2*)&bias[2 * lane];
#pragma unroll
  for (int i = 0; i < 8; ++i) {
    if (r0 + i < n) {
      float2 o = make_float2(fmaxf(acc[i][0] + b2.x, 0.f),
                             fmaxf(acc[i][1] + b2.y, 0.f));
      *(float2*)(out + (size_t)(r0 + i) * 128 + 2 * lane) = o;
    }
  }
}

// [n,128] @ [128,64], no bias/relu. wave = 8 rows, lane = 1 col
__global__ __launch_bounds__(256) void k_gemm3(const float* __restrict__ H,
                                               const float* __restrict__ W,
                                               float* __restrict__ out, int n) {
  __shared__ float ws[128 * 64];
  {
    const float4* W4 = (const float4*)W;
    float4* S4 = (float4*)ws;
    for (int j = threadIdx.x; j < 128 * 64 / 4; j += 256) S4[j] = W4[j];
  }
  __syncthreads();
  int wave = threadIdx.x >> 6, lane = threadIdx.x & 63;
  int r0 = blockIdx.x * 32 + wave * 8;
  if (r0 >= n) return;
  int rr[8];
#pragma unroll
  for (int i = 0; i < 8; ++i) rr[i] = min(r0 + i, n - 1);
  float acc[8] = {};
  for (int k = 0; k < 128; k += 4) {
    float h[8][4];
#pragma unroll
    for (int i = 0; i < 8; ++i) {
      float4 t4 = *(const float4*)(H + (size_t)rr[i] * 128 + k);
      h[i][0] = t4.x; h[i][1] = t4.y; h[i][2] = t4.z; h[i][3] = t4.w;
    }
#pragma unroll
    for (int kk = 0; kk < 4; ++kk) {
      float w = ws[(k + kk) * 64 + lane];
#pragma unroll
      for (int i = 0; i < 8; ++i) acc[i] += h[i][kk] * w;
    }
  }
#pragma unroll
  for (int i = 0; i < 8; ++i)
    if (r0 + i < n) out[(size_t)(r0 + i) * 64 + lane] = acc[i];
}

// ---------------- mean pool over sorted batch (node-parallel) ----------------

__global__ void k_zero(float* __restrict__ p, int n) {
  int i = blockIdx.x * blockDim.x + threadIdx.x;
  if (i < n) p[i] = 0.f;
}

// wave per 16 consecutive nodes, lane = feature; run-sum per graph id
// (batch sorted), flush via atomicAdd at graph boundaries.
__global__ void k_pool1(const float* __restrict__ h, const int* __restrict__ batch,
                        float* __restrict__ sums, int n) {
  int gid = blockIdx.x * blockDim.x + threadIdx.x;
  int w = gid >> 6, f = gid & 63;
  int i0 = w * 16;
  if (i0 >= n) return;
  int i1 = min(i0 + 16, n);
  int cur = batch[i0];
  float acc = 0.f;
  for (int i = i0; i < i1; ++i) {
    int g = batch[i];
    if (g != cur) {
      atomicAdd(&sums[cur * 64 + f], acc);
      acc = 0.f; cur = g;
    }
    acc += h[(size_t)i * 64 + f];
  }
  atomicAdd(&sums[cur * 64 + f], acc);
}

// pooled[g][f] = sums[g][f] / max(cnt(g),1); cnt via binary search on sorted batch
__global__ void k_pool2(const float* __restrict__ sums, const int* __restrict__ batch,
                        float* __restrict__ pooled, int n) {
  int g = blockIdx.x, f = threadIdx.x;
  int lo = 0, hi = n;
  while (lo < hi) { int m = (lo + hi) >> 1; if (batch[m] < g) lo = m + 1; else hi = m; }
  int start = lo;
  hi = n;
  while (lo < hi) { int m = (lo + hi) >> 1; if (batch[m] < g + 1) lo = m + 1; else hi = m; }
  float cnt = (float)(lo - start);
  pooled[g * 64 + f] = sums[g * 64 + f] / fmaxf(cnt, 1.f);
}

// ---------------- launch ----------------

extern "C" void kernel_launch(void* const* d_in, const int* in_sizes, int n_in,
                              void* d_out, int out_size, void* d_ws, size_t ws_size,
                              hipStream_t stream) {
  const float* x   = (const float*)d_in[0];
  const int* eidx  = (const int*)d_in[1];
  const int* batch = (const int*)d_in[2];
  const float* W1  = (const float*)d_in[3];
  const float* b1  = (const float*)d_in[4];
  const float* W2  = (const float*)d_in[5];
  const float* b2  = (const float*)d_in[6];
  const float* W3  = (const float*)d_in[7];
  const float* b3  = (const float*)d_in[8];
  float* out = (float*)d_out;

  const int n = in_sizes[0] / 7;       // 50000
  const int e = in_sizes[1] / 2;       // 800000
  const int G = out_size / 64 - n;     // 50
  const int m = e + n;                 // CSR entries incl self-loops

  // workspace carve-up (4B elements)
  float* wsf = (float*)d_ws;
  int*   wsi = (int*)d_ws;
  size_t off = 0;
  int*   deg    = wsi + off; off += n;
  float* dinv   = wsf + off; off += n;
  int*   rp     = wsi + off; off += (size_t)((n + 1 + 3) & ~3);
  int*   cursor = wsi + off; off += n;
  int*   psum   = wsi + off; off += 256;
  float* sums   = wsf + off; off += (size_t)G * 64;
  int2*  csr    = (int2*)(wsi + off); off += (size_t)2 * m;
  float* bufA   = wsf + off; off += (size_t)n * 128;
  float* bufB   = wsf + off; off += (size_t)n * 128;

  const int* src = eidx;       // edge_index[0]
  const int* dst = eidx + e;   // edge_index[1]

  const int nb = (n + 255) / 256;

  // CSR build
  k_init_deg<<<nb, 256, 0, stream>>>(deg, n);
  k_count<<<(e + 255) / 256, 256, 0, stream>>>(dst, deg, e);
  k_dinv<<<nb, 256, 0, stream>>>(deg, dinv, n);
  k_scan1<<<nb, 256, 0, stream>>>(deg, rp, psum, n);
  k_scan2<<<1, 256, 0, stream>>>(psum, nb);
  k_scan3<<<nb, 256, 0, stream>>>(rp, cursor, psum, n, m);
  k_scatter<<<(m + 255) / 256, 256, 0, stream>>>(src, dst, dinv, cursor, csr, e, n);
  // zero pooled sums (harness doesn't re-poison between replays)
  k_zero<<<(G * 64 + 255) / 256, 256, 0, stream>>>(sums, G * 64);

  // layer 1: AGG(x) [n,7] then @W1 + b1, relu  (AGG and linear commute)
  k_agg7<<<((size_t)n * 64 + 255) / 256, 256, 0, stream>>>(x, csr, rp, bufA, n);
  k_gemm1<<<(n + 1) / 2, 256, 0, stream>>>(bufA, W1, b1, bufB, n);

  // layer 2: AGG(h1) [n,128] then @W2 + b2, relu
  k_agg128<<<((size_t)n * 64 + 255) / 256, 256, 0, stream>>>(bufB, csr, rp, bufA, n);
  k_gemm2<<<(n + 31) / 32, 256, 0, stream>>>(bufA, W2, b2, bufB, n);

  // layer 3: h2 @ W3 [n,64] then AGG + b3 -> d_out
  k_gemm3<<<(n + 31) / 32, 256, 0, stream>>>(bufB, W3, bufA, n);
  k_agg64b<<<((size_t)n * 64 + 255) / 256, 256, 0, stream>>>(bufA, csr, rp, b3, out, n);

  // mean pool -> d_out tail (node-parallel + finalize)
  const int waves = (n + 15) / 16;
  k_pool1<<<(waves * 64 + 255) / 256, 256, 0, stream>>>(out, batch, sums, n);
  k_pool2<<<G, 64, 0, stream>>>(sums, batch, out + (size_t)n * 64, n);
}

// Round 5
// 385.589 us; speedup vs baseline: 1.3631x; 1.0017x over previous
//
#include <hip/hip_runtime.h>

// ---------------- degree / CSR build ----------------

__global__ void k_init_deg(int* __restrict__ deg, int n) {
  int i = blockIdx.x * blockDim.x + threadIdx.x;
  if (i < n) deg[i] = 1;  // self-loop
}

__global__ void k_count(const int* __restrict__ dst, int* __restrict__ deg, int e) {
  int i = blockIdx.x * blockDim.x + threadIdx.x;
  if (i < e) atomicAdd(&deg[dst[i]], 1);
}

__global__ void k_dinv(const int* __restrict__ deg, float* __restrict__ dinv, int n) {
  int i = blockIdx.x * blockDim.x + threadIdx.x;
  if (i < n) dinv[i] = rsqrtf((float)deg[i]);
}

__global__ void k_scan1(const int* __restrict__ deg, int* __restrict__ rp,
                        int* __restrict__ psum, int n) {
  __shared__ int s[256];
  int tid = threadIdx.x;
  int i = blockIdx.x * 256 + tid;
  int v = (i < n) ? deg[i] : 0;
  int x = v;
  s[tid] = x; __syncthreads();
  for (int off = 1; off < 256; off <<= 1) {
    int t = (tid >= off) ? s[tid - off] : 0;
    __syncthreads();
    x += t; s[tid] = x;
    __syncthreads();
  }
  if (i < n) rp[i] = x - v;                 // exclusive within block
  if (tid == 255) psum[blockIdx.x] = x;     // block total
}

__global__ void k_scan2(int* __restrict__ psum, int nb) {
  __shared__ int s[256];
  int tid = threadIdx.x;
  int v = (tid < nb) ? psum[tid] : 0;
  int x = v;
  s[tid] = x; __syncthreads();
  for (int off = 1; off < 256; off <<= 1) {
    int t = (tid >= off) ? s[tid - off] : 0;
    __syncthreads();
    x += t; s[tid] = x;
    __syncthreads();
  }
  if (tid < nb) psum[tid] = x - v;          // exclusive prefix of block sums
}

__global__ void k_scan3(int* __restrict__ rp, int* __restrict__ cursor,
                        const int* __restrict__ psum, int n, int total) {
  int i = blockIdx.x * blockDim.x + threadIdx.x;
  if (i < n) {
    int r = rp[i] + psum[i >> 8];
    rp[i] = r;
    cursor[i] = r;
  }
  if (i == 0) rp[n] = total;
}

__global__ void k_scatter(const int* __restrict__ src, const int* __restrict__ dst,
                          const float* __restrict__ dinv, int* __restrict__ cursor,
                          int2* __restrict__ csr, int e, int n) {
  int i = blockIdx.x * blockDim.x + threadIdx.x;
  if (i >= e + n) return;
  int s, d;
  if (i < e) { s = src[i]; d = dst[i]; }
  else       { s = d = i - e; }             // self-loop
  int pos = atomicAdd(&cursor[d], 1);
  float w = dinv[s] * dinv[d];
  csr[pos] = make_int2(s, __float_as_int(w));
}

// ---------------- aggregation (pull, CSR by dst) ----------------

// width-7 aggregation on raw x: lane per edge + butterfly reduce
__global__ void k_agg7(const float* __restrict__ x, const int2* __restrict__ csr,
                       const int* __restrict__ rp, float* __restrict__ out, int n) {
  int gid = blockIdx.x * blockDim.x + threadIdx.x;
  int v = gid >> 6, lane = gid & 63;
  if (v >= n) return;
  int beg = rp[v], end = rp[v + 1];
  float a[7] = {0.f, 0.f, 0.f, 0.f, 0.f, 0.f, 0.f};
  for (int base = beg; base < end; base += 64) {
    int cnt = end - base; if (cnt > 64) cnt = 64;
    if (lane < cnt) {
      int2 e = csr[base + lane];
      float w = __int_as_float(e.y);
      const float* xr = x + (size_t)e.x * 7;
#pragma unroll
      for (int f = 0; f < 7; ++f) a[f] += w * xr[f];
    }
  }
#pragma unroll
  for (int off = 32; off > 0; off >>= 1) {
#pragma unroll
    for (int f = 0; f < 7; ++f) a[f] += __shfl_xor(a[f], off);
  }
  if (lane == 0) {
#pragma unroll
    for (int f = 0; f < 7; ++f) out[(size_t)v * 7 + f] = a[f];
  }
}

// width-128 aggregation: 32 lanes per node (2 nodes/wave), float4 per lane.
// One load instruction = one full 512B row; unroll x4 -> 4 rows in flight
// per half-wave (2x the prior MLP at half the instruction count).
__global__ void k_agg128(const float* __restrict__ t, const int2* __restrict__ csr,
                         const int* __restrict__ rp, float* __restrict__ out, int n) {
  int gid = blockIdx.x * blockDim.x + threadIdx.x;
  int v = gid >> 5, lane = gid & 31;
  if (v >= n) return;
  int beg = rp[v], end = rp[v + 1];
  float4 a = make_float4(0.f, 0.f, 0.f, 0.f);
  const float4* tp = (const float4*)t + lane;   // row stride = 32 float4
  for (int base = beg; base < end; base += 32) {
    int cnt = end - base; if (cnt > 32) cnt = 32;
    int2 e = csr[base + (lane < cnt ? lane : cnt - 1)];
    int j = 0;
    for (; j + 4 <= cnt; j += 4) {
      int s0 = __shfl(e.x, j + 0, 32), s1 = __shfl(e.x, j + 1, 32);
      int s2 = __shfl(e.x, j + 2, 32), s3 = __shfl(e.x, j + 3, 32);
      float w0 = __int_as_float(__shfl(e.y, j + 0, 32));
      float w1 = __int_as_float(__shfl(e.y, j + 1, 32));
      float w2 = __int_as_float(__shfl(e.y, j + 2, 32));
      float w3 = __int_as_float(__shfl(e.y, j + 3, 32));
      float4 r0 = tp[(size_t)s0 * 32];
      float4 r1 = tp[(size_t)s1 * 32];
      float4 r2 = tp[(size_t)s2 * 32];
      float4 r3 = tp[(size_t)s3 * 32];
      a.x += w0 * r0.x; a.y += w0 * r0.y; a.z += w0 * r0.z; a.w += w0 * r0.w;
      a.x += w1 * r1.x; a.y += w1 * r1.y; a.z += w1 * r1.z; a.w += w1 * r1.w;
      a.x += w2 * r2.x; a.y += w2 * r2.y; a.z += w2 * r2.z; a.w += w2 * r2.w;
      a.x += w3 * r3.x; a.y += w3 * r3.y; a.z += w3 * r3.z; a.w += w3 * r3.w;
    }
    for (; j < cnt; ++j) {
      int s0 = __shfl(e.x, j, 32);
      float w0 = __int_as_float(__shfl(e.y, j, 32));
      float4 r0 = tp[(size_t)s0 * 32];
      a.x += w0 * r0.x; a.y += w0 * r0.y; a.z += w0 * r0.z; a.w += w0 * r0.w;
    }
  }
  ((float4*)(out + (size_t)v * 128))[lane] = a;
}

// width-64 aggregation + bias: 16 lanes per node (4 nodes/wave), float4 per lane.
__global__ void k_agg64b(const float* __restrict__ t, const int2* __restrict__ csr,
                         const int* __restrict__ rp, const float* __restrict__ bias,
                         float* __restrict__ out, int n) {
  int gid = blockIdx.x * blockDim.x + threadIdx.x;
  int v = gid >> 4, lane = gid & 15;
  if (v >= n) return;
  int beg = rp[v], end = rp[v + 1];
  float4 a = make_float4(0.f, 0.f, 0.f, 0.f);
  const float4* tp = (const float4*)t + lane;   // row stride = 16 float4
  for (int base = beg; base < end; base += 16) {
    int cnt = end - base; if (cnt > 16) cnt = 16;
    int2 e = csr[base + (lane < cnt ? lane : cnt - 1)];
    int j = 0;
    for (; j + 4 <= cnt; j += 4) {
      int s0 = __shfl(e.x, j + 0, 16), s1 = __shfl(e.x, j + 1, 16);
      int s2 = __shfl(e.x, j + 2, 16), s3 = __shfl(e.x, j + 3, 16);
      float w0 = __int_as_float(__shfl(e.y, j + 0, 16));
      float w1 = __int_as_float(__shfl(e.y, j + 1, 16));
      float w2 = __int_as_float(__shfl(e.y, j + 2, 16));
      float w3 = __int_as_float(__shfl(e.y, j + 3, 16));
      float4 r0 = tp[(size_t)s0 * 16];
      float4 r1 = tp[(size_t)s1 * 16];
      float4 r2 = tp[(size_t)s2 * 16];
      float4 r3 = tp[(size_t)s3 * 16];
      a.x += w0 * r0.x; a.y += w0 * r0.y; a.z += w0 * r0.z; a.w += w0 * r0.w;
      a.x += w1 * r1.x; a.y += w1 * r1.y; a.z += w1 * r1.z; a.w += w1 * r1.w;
      a.x += w2 * r2.x; a.y += w2 * r2.y; a.z += w2 * r2.z; a.w += w2 * r2.w;
      a.x += w3 * r3.x; a.y += w3 * r3.y; a.z += w3 * r3.z; a.w += w3 * r3.w;
    }
    for (; j < cnt; ++j) {
      int s0 = __shfl(e.x, j, 16);
      float w0 = __int_as_float(__shfl(e.y, j, 16));
      float4 r0 = tp[(size_t)s0 * 16];
      a.x += w0 * r0.x; a.y += w0 * r0.y; a.z += w0 * r0.z; a.w += w0 * r0.w;
    }
  }
  const float4 b4 = ((const float4*)bias)[lane];
  a.x += b4.x; a.y += b4.y; a.z += b4.z; a.w += b4.w;
  ((float4*)(out + (size_t)v * 64))[lane] = a;
}

// ---------------- GEMMs (fp32, vector ALU) ----------------

// [n,7] @ [7,128] + b, relu. block = 2 rows x 128 cols
__global__ __launch_bounds__(256) void k_gemm1(const float* __restrict__ A,
                                               const float* __restrict__ W,
                                               const float* __restrict__ bias,
                                               float* __restrict__ out, int n) {
  __shared__ float ws[7 * 128];
  for (int j = threadIdx.x; j < 7 * 128; j += 256) ws[j] = W[j];
  __syncthreads();
  int r = blockIdx.x * 2 + (threadIdx.x >> 7);
  int c = threadIdx.x & 127;
  if (r >= n) return;
  const float* a = A + (size_t)r * 7;
  float acc = bias[c];
#pragma unroll
  for (int k = 0; k < 7; ++k) acc += a[k] * ws[k * 128 + c];
  out[(size_t)r * 128 + c] = fmaxf(acc, 0.f);
}

// [n,128] @ [128,128] + b, relu. W staged in two 32KB k-halves.
__global__ __launch_bounds__(256) void k_gemm2(const float* __restrict__ H,
                                               const float* __restrict__ W,
                                               const float* __restrict__ bias,
                                               float* __restrict__ out, int n) {
  __shared__ float ws[64 * 128];  // 32 KiB
  int wave = threadIdx.x >> 6, lane = threadIdx.x & 63;
  int r0 = blockIdx.x * 32 + wave * 8;
  int rr[8];
#pragma unroll
  for (int i = 0; i < 8; ++i) rr[i] = min(r0 + i, n - 1);
  float acc[8][2] = {};

#pragma unroll
  for (int half = 0; half < 2; ++half) {
    {
      const float4* W4 = (const float4*)(W + half * 64 * 128);
      float4* S4 = (float4*)ws;
      for (int j = threadIdx.x; j < 64 * 128 / 4; j += 256) S4[j] = W4[j];
    }
    __syncthreads();
    const float* Hh = H + half * 64;
    for (int k = 0; k < 64; k += 4) {
      float h[8][4];
#pragma unroll
      for (int i = 0; i < 8; ++i) {
        float4 t4 = *(const float4*)(Hh + (size_t)rr[i] * 128 + k);
        h[i][0] = t4.x; h[i][1] = t4.y; h[i][2] = t4.z; h[i][3] = t4.w;
      }
#pragma unroll
      for (int kk = 0; kk < 4; ++kk) {
        float2 w2 = *(const float2*)&ws[(k + kk) * 128 + 2 * lane];
#pragma unroll
        for (int i = 0; i < 8; ++i) {
          acc[i][0] += h[i][kk] * w2.x;
          acc[i][1] += h[i][kk] * w2.y;
        }
      }
    }
    __syncthreads();
  }

  float2 b2 = *(const float2*)&bias[2 * lane];
#pragma unroll
  for (int i = 0; i < 8; ++i) {
    if (r0 + i < n) {
      float2 o = make_float2(fmaxf(acc[i][0] + b2.x, 0.f),
                             fmaxf(acc[i][1] + b2.y, 0.f));
      *(float2*)(out + (size_t)(r0 + i) * 128 + 2 * lane) = o;
    }
  }
}

// [n,128] @ [128,64], no bias/relu. wave = 8 rows, lane = 1 col
__global__ __launch_bounds__(256) void k_gemm3(const float* __restrict__ H,
                                               const float* __restrict__ W,
                                               float* __restrict__ out, int n) {
  __shared__ float ws[128 * 64];
  {
    const float4* W4 = (const float4*)W;
    float4* S4 = (float4*)ws;
    for (int j = threadIdx.x; j < 128 * 64 / 4; j += 256) S4[j] = W4[j];
  }
  __syncthreads();
  int wave = threadIdx.x >> 6, lane = threadIdx.x & 63;
  int r0 = blockIdx.x * 32 + wave * 8;
  if (r0 >= n) return;
  int rr[8];
#pragma unroll
  for (int i = 0; i < 8; ++i) rr[i] = min(r0 + i, n - 1);
  float acc[8] = {};
  for (int k = 0; k < 128; k += 4) {
    float h[8][4];
#pragma unroll
    for (int i = 0; i < 8; ++i) {
      float4 t4 = *(const float4*)(H + (size_t)rr[i] * 128 + k);
      h[i][0] = t4.x; h[i][1] = t4.y; h[i][2] = t4.z; h[i][3] = t4.w;
    }
#pragma unroll
    for (int kk = 0; kk < 4; ++kk) {
      float w = ws[(k + kk) * 64 + lane];
#pragma unroll
      for (int i = 0; i < 8; ++i) acc[i] += h[i][kk] * w;
    }
  }
#pragma unroll
  for (int i = 0; i < 8; ++i)
    if (r0 + i < n) out[(size_t)(r0 + i) * 64 + lane] = acc[i];
}

// ---------------- mean pool over sorted batch (node-parallel) ----------------

__global__ void k_zero(float* __restrict__ p, int n) {
  int i = blockIdx.x * blockDim.x + threadIdx.x;
  if (i < n) p[i] = 0.f;
}

// wave per 16 consecutive nodes, lane = feature; run-sum per graph id
// (batch sorted), flush via atomicAdd at graph boundaries.
__global__ void k_pool1(const float* __restrict__ h, const int* __restrict__ batch,
                        float* __restrict__ sums, int n) {
  int gid = blockIdx.x * blockDim.x + threadIdx.x;
  int w = gid >> 6, f = gid & 63;
  int i0 = w * 16;
  if (i0 >= n) return;
  int i1 = min(i0 + 16, n);
  int cur = batch[i0];
  float acc = 0.f;
  for (int i = i0; i < i1; ++i) {
    int g = batch[i];
    if (g != cur) {
      atomicAdd(&sums[cur * 64 + f], acc);
      acc = 0.f; cur = g;
    }
    acc += h[(size_t)i * 64 + f];
  }
  atomicAdd(&sums[cur * 64 + f], acc);
}

// pooled[g][f] = sums[g][f] / max(cnt(g),1); cnt via binary search on sorted batch
__global__ void k_pool2(const float* __restrict__ sums, const int* __restrict__ batch,
                        float* __restrict__ pooled, int n) {
  int g = blockIdx.x, f = threadIdx.x;
  int lo = 0, hi = n;
  while (lo < hi) { int m = (lo + hi) >> 1; if (batch[m] < g) lo = m + 1; else hi = m; }
  int start = lo;
  hi = n;
  while (lo < hi) { int m = (lo + hi) >> 1; if (batch[m] < g + 1) lo = m + 1; else hi = m; }
  float cnt = (float)(lo - start);
  pooled[g * 64 + f] = sums[g * 64 + f] / fmaxf(cnt, 1.f);
}

// ---------------- launch ----------------

extern "C" void kernel_launch(void* const* d_in, const int* in_sizes, int n_in,
                              void* d_out, int out_size, void* d_ws, size_t ws_size,
                              hipStream_t stream) {
  const float* x   = (const float*)d_in[0];
  const int* eidx  = (const int*)d_in[1];
  const int* batch = (const int*)d_in[2];
  const float* W1  = (const float*)d_in[3];
  const float* b1  = (const float*)d_in[4];
  const float* W2  = (const float*)d_in[5];
  const float* b2  = (const float*)d_in[6];
  const float* W3  = (const float*)d_in[7];
  const float* b3  = (const float*)d_in[8];
  float* out = (float*)d_out;

  const int n = in_sizes[0] / 7;       // 50000
  const int e = in_sizes[1] / 2;       // 800000
  const int G = out_size / 64 - n;     // 50
  const int m = e + n;                 // CSR entries incl self-loops

  // workspace carve-up (4B elements)
  float* wsf = (float*)d_ws;
  int*   wsi = (int*)d_ws;
  size_t off = 0;
  int*   deg    = wsi + off; off += n;
  float* dinv   = wsf + off; off += n;
  int*   rp     = wsi + off; off += (size_t)((n + 1 + 3) & ~3);
  int*   cursor = wsi + off; off += n;
  int*   psum   = wsi + off; off += 256;
  float* sums   = wsf + off; off += (size_t)G * 64;
  int2*  csr    = (int2*)(wsi + off); off += (size_t)2 * m;
  float* bufA   = wsf + off; off += (size_t)n * 128;
  float* bufB   = wsf + off; off += (size_t)n * 128;

  const int* src = eidx;       // edge_index[0]
  const int* dst = eidx + e;   // edge_index[1]

  const int nb = (n + 255) / 256;

  // CSR build
  k_init_deg<<<nb, 256, 0, stream>>>(deg, n);
  k_count<<<(e + 255) / 256, 256, 0, stream>>>(dst, deg, e);
  k_dinv<<<nb, 256, 0, stream>>>(deg, dinv, n);
  k_scan1<<<nb, 256, 0, stream>>>(deg, rp, psum, n);
  k_scan2<<<1, 256, 0, stream>>>(psum, nb);
  k_scan3<<<nb, 256, 0, stream>>>(rp, cursor, psum, n, m);
  k_scatter<<<(m + 255) / 256, 256, 0, stream>>>(src, dst, dinv, cursor, csr, e, n);
  // zero pooled sums (harness doesn't re-poison between replays)
  k_zero<<<(G * 64 + 255) / 256, 256, 0, stream>>>(sums, G * 64);

  // layer 1: AGG(x) [n,7] then @W1 + b1, relu  (AGG and linear commute)
  k_agg7<<<((size_t)n * 64 + 255) / 256, 256, 0, stream>>>(x, csr, rp, bufA, n);
  k_gemm1<<<(n + 1) / 2, 256, 0, stream>>>(bufA, W1, b1, bufB, n);

  // layer 2: AGG(h1) [n,128] then @W2 + b2, relu
  k_agg128<<<((size_t)n * 32 + 255) / 256, 256, 0, stream>>>(bufB, csr, rp, bufA, n);
  k_gemm2<<<(n + 31) / 32, 256, 0, stream>>>(bufA, W2, b2, bufB, n);

  // layer 3: h2 @ W3 [n,64] then AGG + b3 -> d_out
  k_gemm3<<<(n + 31) / 32, 256, 0, stream>>>(bufB, W3, bufA, n);
  k_agg64b<<<((size_t)n * 16 + 255) / 256, 256, 0, stream>>>(bufA, csr, rp, b3, out, n);

  // mean pool -> d_out tail (node-parallel + finalize)
  const int waves = (n + 15) / 16;
  k_pool1<<<(waves * 64 + 255) / 256, 256, 0, stream>>>(out, batch, sums, n);
  k_pool2<<<G, 64, 0, stream>>>(sums, batch, out + (size_t)n * 64, n);
}

// Round 6
// 334.570 us; speedup vs baseline: 1.5709x; 1.1525x over previous
//
#include <hip/hip_runtime.h>

// bf16 helpers (manual, round-to-nearest-even)
__device__ __forceinline__ unsigned short f2bf(float f) {
  unsigned int u = __float_as_uint(f);
  unsigned int r = (u + 0x7FFFu + ((u >> 16) & 1u)) >> 16;
  return (unsigned short)r;
}
__device__ __forceinline__ float bf_lo(unsigned int u) { return __uint_as_float(u << 16); }
__device__ __forceinline__ float bf_hi(unsigned int u) { return __uint_as_float(u & 0xFFFF0000u); }

// ---------------- degree / CSR build ----------------

__global__ void k_init_deg(int* __restrict__ deg, int n) {
  int i = blockIdx.x * blockDim.x + threadIdx.x;
  if (i < n) deg[i] = 1;  // self-loop
}

__global__ void k_count(const int* __restrict__ dst, int* __restrict__ deg, int e) {
  int i = blockIdx.x * blockDim.x + threadIdx.x;
  if (i < e) atomicAdd(&deg[dst[i]], 1);
}

__global__ void k_dinv(const int* __restrict__ deg, float* __restrict__ dinv, int n) {
  int i = blockIdx.x * blockDim.x + threadIdx.x;
  if (i < n) dinv[i] = rsqrtf((float)deg[i]);
}

__global__ void k_scan1(const int* __restrict__ deg, int* __restrict__ rp,
                        int* __restrict__ psum, int n) {
  __shared__ int s[256];
  int tid = threadIdx.x;
  int i = blockIdx.x * 256 + tid;
  int v = (i < n) ? deg[i] : 0;
  int x = v;
  s[tid] = x; __syncthreads();
  for (int off = 1; off < 256; off <<= 1) {
    int t = (tid >= off) ? s[tid - off] : 0;
    __syncthreads();
    x += t; s[tid] = x;
    __syncthreads();
  }
  if (i < n) rp[i] = x - v;                 // exclusive within block
  if (tid == 255) psum[blockIdx.x] = x;     // block total
}

__global__ void k_scan2(int* __restrict__ psum, int nb) {
  __shared__ int s[256];
  int tid = threadIdx.x;
  int v = (tid < nb) ? psum[tid] : 0;
  int x = v;
  s[tid] = x; __syncthreads();
  for (int off = 1; off < 256; off <<= 1) {
    int t = (tid >= off) ? s[tid - off] : 0;
    __syncthreads();
    x += t; s[tid] = x;
    __syncthreads();
  }
  if (tid < nb) psum[tid] = x - v;          // exclusive prefix of block sums
}

__global__ void k_scan3(int* __restrict__ rp, int* __restrict__ cursor,
                        const int* __restrict__ psum, int n, int total) {
  int i = blockIdx.x * blockDim.x + threadIdx.x;
  if (i < n) {
    int r = rp[i] + psum[i >> 8];
    rp[i] = r;
    cursor[i] = r;
  }
  if (i == 0) rp[n] = total;
}

__global__ void k_scatter(const int* __restrict__ src, const int* __restrict__ dst,
                          const float* __restrict__ dinv, int* __restrict__ cursor,
                          int2* __restrict__ csr, int e, int n) {
  int i = blockIdx.x * blockDim.x + threadIdx.x;
  if (i >= e + n) return;
  int s, d;
  if (i < e) { s = src[i]; d = dst[i]; }
  else       { s = d = i - e; }             // self-loop
  int pos = atomicAdd(&cursor[d], 1);
  float w = dinv[s] * dinv[d];
  csr[pos] = make_int2(s, __float_as_int(w));
}

// ---------------- aggregation (pull, CSR by dst) ----------------

// width-7 aggregation on raw x: lane per edge + butterfly reduce
__global__ void k_agg7(const float* __restrict__ x, const int2* __restrict__ csr,
                       const int* __restrict__ rp, float* __restrict__ out, int n) {
  int gid = blockIdx.x * blockDim.x + threadIdx.x;
  int v = gid >> 6, lane = gid & 63;
  if (v >= n) return;
  int beg = rp[v], end = rp[v + 1];
  float a[7] = {0.f, 0.f, 0.f, 0.f, 0.f, 0.f, 0.f};
  for (int base = beg; base < end; base += 64) {
    int cnt = end - base; if (cnt > 64) cnt = 64;
    if (lane < cnt) {
      int2 e = csr[base + lane];
      float w = __int_as_float(e.y);
      const float* xr = x + (size_t)e.x * 7;
#pragma unroll
      for (int f = 0; f < 7; ++f) a[f] += w * xr[f];
    }
  }
#pragma unroll
  for (int off = 32; off > 0; off >>= 1) {
#pragma unroll
    for (int f = 0; f < 7; ++f) a[f] += __shfl_xor(a[f], off);
  }
  if (lane == 0) {
#pragma unroll
    for (int f = 0; f < 7; ++f) out[(size_t)v * 7 + f] = a[f];
  }
}

// width-128 bf16 aggregation: 32 lanes per node (2 nodes/wave), uint2 (4 bf16)
// per lane -> 256B row. fp32 accumulate, fp32 out.
__global__ void k_agg128(const unsigned short* __restrict__ t, const int2* __restrict__ csr,
                         const int* __restrict__ rp, float* __restrict__ out, int n) {
  int gid = blockIdx.x * blockDim.x + threadIdx.x;
  int v = gid >> 5, lane = gid & 31;
  if (v >= n) return;
  int beg = rp[v], end = rp[v + 1];
  float4 a = make_float4(0.f, 0.f, 0.f, 0.f);
  const uint2* tp = (const uint2*)t + lane;   // row stride = 32 uint2 (128 bf16)
  for (int base = beg; base < end; base += 32) {
    int cnt = end - base; if (cnt > 32) cnt = 32;
    int2 e = csr[base + (lane < cnt ? lane : cnt - 1)];
    int j = 0;
    for (; j + 4 <= cnt; j += 4) {
      int s0 = __shfl(e.x, j + 0, 32), s1 = __shfl(e.x, j + 1, 32);
      int s2 = __shfl(e.x, j + 2, 32), s3 = __shfl(e.x, j + 3, 32);
      float w0 = __int_as_float(__shfl(e.y, j + 0, 32));
      float w1 = __int_as_float(__shfl(e.y, j + 1, 32));
      float w2 = __int_as_float(__shfl(e.y, j + 2, 32));
      float w3 = __int_as_float(__shfl(e.y, j + 3, 32));
      uint2 r0 = tp[(size_t)s0 * 32];
      uint2 r1 = tp[(size_t)s1 * 32];
      uint2 r2 = tp[(size_t)s2 * 32];
      uint2 r3 = tp[(size_t)s3 * 32];
      a.x += w0 * bf_lo(r0.x); a.y += w0 * bf_hi(r0.x); a.z += w0 * bf_lo(r0.y); a.w += w0 * bf_hi(r0.y);
      a.x += w1 * bf_lo(r1.x); a.y += w1 * bf_hi(r1.x); a.z += w1 * bf_lo(r1.y); a.w += w1 * bf_hi(r1.y);
      a.x += w2 * bf_lo(r2.x); a.y += w2 * bf_hi(r2.x); a.z += w2 * bf_lo(r2.y); a.w += w2 * bf_hi(r2.y);
      a.x += w3 * bf_lo(r3.x); a.y += w3 * bf_hi(r3.x); a.z += w3 * bf_lo(r3.y); a.w += w3 * bf_hi(r3.y);
    }
    for (; j < cnt; ++j) {
      int s0 = __shfl(e.x, j, 32);
      float w0 = __int_as_float(__shfl(e.y, j, 32));
      uint2 r0 = tp[(size_t)s0 * 32];
      a.x += w0 * bf_lo(r0.x); a.y += w0 * bf_hi(r0.x); a.z += w0 * bf_lo(r0.y); a.w += w0 * bf_hi(r0.y);
    }
  }
  ((float4*)(out + (size_t)v * 128))[lane] = a;
}

// width-64 bf16 aggregation + bias: 16 lanes per node (4 nodes/wave), uint2 per
// lane -> 128B row = ONE cache line per edge. fp32 accumulate, fp32 out.
__global__ void k_agg64b(const unsigned short* __restrict__ t, const int2* __restrict__ csr,
                         const int* __restrict__ rp, const float* __restrict__ bias,
                         float* __restrict__ out, int n) {
  int gid = blockIdx.x * blockDim.x + threadIdx.x;
  int v = gid >> 4, lane = gid & 15;
  if (v >= n) return;
  int beg = rp[v], end = rp[v + 1];
  float4 a = make_float4(0.f, 0.f, 0.f, 0.f);
  const uint2* tp = (const uint2*)t + lane;   // row stride = 16 uint2 (64 bf16)
  for (int base = beg; base < end; base += 16) {
    int cnt = end - base; if (cnt > 16) cnt = 16;
    int2 e = csr[base + (lane < cnt ? lane : cnt - 1)];
    int j = 0;
    for (; j + 4 <= cnt; j += 4) {
      int s0 = __shfl(e.x, j + 0, 16), s1 = __shfl(e.x, j + 1, 16);
      int s2 = __shfl(e.x, j + 2, 16), s3 = __shfl(e.x, j + 3, 16);
      float w0 = __int_as_float(__shfl(e.y, j + 0, 16));
      float w1 = __int_as_float(__shfl(e.y, j + 1, 16));
      float w2 = __int_as_float(__shfl(e.y, j + 2, 16));
      float w3 = __int_as_float(__shfl(e.y, j + 3, 16));
      uint2 r0 = tp[(size_t)s0 * 16];
      uint2 r1 = tp[(size_t)s1 * 16];
      uint2 r2 = tp[(size_t)s2 * 16];
      uint2 r3 = tp[(size_t)s3 * 16];
      a.x += w0 * bf_lo(r0.x); a.y += w0 * bf_hi(r0.x); a.z += w0 * bf_lo(r0.y); a.w += w0 * bf_hi(r0.y);
      a.x += w1 * bf_lo(r1.x); a.y += w1 * bf_hi(r1.x); a.z += w1 * bf_lo(r1.y); a.w += w1 * bf_hi(r1.y);
      a.x += w2 * bf_lo(r2.x); a.y += w2 * bf_hi(r2.x); a.z += w2 * bf_lo(r2.y); a.w += w2 * bf_hi(r2.y);
      a.x += w3 * bf_lo(r3.x); a.y += w3 * bf_hi(r3.x); a.z += w3 * bf_lo(r3.y); a.w += w3 * bf_hi(r3.y);
    }
    for (; j < cnt; ++j) {
      int s0 = __shfl(e.x, j, 16);
      float w0 = __int_as_float(__shfl(e.y, j, 16));
      uint2 r0 = tp[(size_t)s0 * 16];
      a.x += w0 * bf_lo(r0.x); a.y += w0 * bf_hi(r0.x); a.z += w0 * bf_lo(r0.y); a.w += w0 * bf_hi(r0.y);
    }
  }
  const float4 b4 = ((const float4*)bias)[lane];
  a.x += b4.x; a.y += b4.y; a.z += b4.z; a.w += b4.w;
  ((float4*)(out + (size_t)v * 64))[lane] = a;
}

// ---------------- GEMMs (fp32, vector ALU) ----------------

// [n,7] @ [7,128] + b, relu -> bf16 out. block = 2 rows x 128 cols
__global__ __launch_bounds__(256) void k_gemm1(const float* __restrict__ A,
                                               const float* __restrict__ W,
                                               const float* __restrict__ bias,
                                               unsigned short* __restrict__ out, int n) {
  __shared__ float ws[7 * 128];
  for (int j = threadIdx.x; j < 7 * 128; j += 256) ws[j] = W[j];
  __syncthreads();
  int r = blockIdx.x * 2 + (threadIdx.x >> 7);
  int c = threadIdx.x & 127;
  if (r >= n) return;
  const float* a = A + (size_t)r * 7;
  float acc = bias[c];
#pragma unroll
  for (int k = 0; k < 7; ++k) acc += a[k] * ws[k * 128 + c];
  out[(size_t)r * 128 + c] = f2bf(fmaxf(acc, 0.f));
}

// [n,128] @ [128,128] + b, relu. W staged in two 32KB k-halves. fp32 in/out.
__global__ __launch_bounds__(256) void k_gemm2(const float* __restrict__ H,
                                               const float* __restrict__ W,
                                               const float* __restrict__ bias,
                                               float* __restrict__ out, int n) {
  __shared__ float ws[64 * 128];  // 32 KiB
  int wave = threadIdx.x >> 6, lane = threadIdx.x & 63;
  int r0 = blockIdx.x * 32 + wave * 8;
  int rr[8];
#pragma unroll
  for (int i = 0; i < 8; ++i) rr[i] = min(r0 + i, n - 1);
  float acc[8][2] = {};

#pragma unroll
  for (int half = 0; half < 2; ++half) {
    {
      const float4* W4 = (const float4*)(W + half * 64 * 128);
      float4* S4 = (float4*)ws;
      for (int j = threadIdx.x; j < 64 * 128 / 4; j += 256) S4[j] = W4[j];
    }
    __syncthreads();
    const float* Hh = H + half * 64;
    for (int k = 0; k < 64; k += 4) {
      float h[8][4];
#pragma unroll
      for (int i = 0; i < 8; ++i) {
        float4 t4 = *(const float4*)(Hh + (size_t)rr[i] * 128 + k);
        h[i][0] = t4.x; h[i][1] = t4.y; h[i][2] = t4.z; h[i][3] = t4.w;
      }
#pragma unroll
      for (int kk = 0; kk < 4; ++kk) {
        float2 w2 = *(const float2*)&ws[(k + kk) * 128 + 2 * lane];
#pragma unroll
        for (int i = 0; i < 8; ++i) {
          acc[i][0] += h[i][kk] * w2.x;
          acc[i][1] += h[i][kk] * w2.y;
        }
      }
    }
    __syncthreads();
  }

  float2 b2 = *(const float2*)&bias[2 * lane];
#pragma unroll
  for (int i = 0; i < 8; ++i) {
    if (r0 + i < n) {
      float2 o = make_float2(fmaxf(acc[i][0] + b2.x, 0.f),
                             fmaxf(acc[i][1] + b2.y, 0.f));
      *(float2*)(out + (size_t)(r0 + i) * 128 + 2 * lane) = o;
    }
  }
}

// [n,128] @ [128,64] -> bf16 out, no bias/relu. wave = 8 rows, lane = 1 col
__global__ __launch_bounds__(256) void k_gemm3(const float* __restrict__ H,
                                               const float* __restrict__ W,
                                               unsigned short* __restrict__ out, int n) {
  __shared__ float ws[128 * 64];
  {
    const float4* W4 = (const float4*)W;
    float4* S4 = (float4*)ws;
    for (int j = threadIdx.x; j < 128 * 64 / 4; j += 256) S4[j] = W4[j];
  }
  __syncthreads();
  int wave = threadIdx.x >> 6, lane = threadIdx.x & 63;
  int r0 = blockIdx.x * 32 + wave * 8;
  if (r0 >= n) return;
  int rr[8];
#pragma unroll
  for (int i = 0; i < 8; ++i) rr[i] = min(r0 + i, n - 1);
  float acc[8] = {};
  for (int k = 0; k < 128; k += 4) {
    float h[8][4];
#pragma unroll
    for (int i = 0; i < 8; ++i) {
      float4 t4 = *(const float4*)(H + (size_t)rr[i] * 128 + k);
      h[i][0] = t4.x; h[i][1] = t4.y; h[i][2] = t4.z; h[i][3] = t4.w;
    }
#pragma unroll
    for (int kk = 0; kk < 4; ++kk) {
      float w = ws[(k + kk) * 64 + lane];
#pragma unroll
      for (int i = 0; i < 8; ++i) acc[i] += h[i][kk] * w;
    }
  }
#pragma unroll
  for (int i = 0; i < 8; ++i)
    if (r0 + i < n) out[(size_t)(r0 + i) * 64 + lane] = f2bf(acc[i]);
}

// ---------------- mean pool over sorted batch (node-parallel) ----------------

__global__ void k_zero(float* __restrict__ p, int n) {
  int i = blockIdx.x * blockDim.x + threadIdx.x;
  if (i < n) p[i] = 0.f;
}

__global__ void k_pool1(const float* __restrict__ h, const int* __restrict__ batch,
                        float* __restrict__ sums, int n) {
  int gid = blockIdx.x * blockDim.x + threadIdx.x;
  int w = gid >> 6, f = gid & 63;
  int i0 = w * 16;
  if (i0 >= n) return;
  int i1 = min(i0 + 16, n);
  int cur = batch[i0];
  float acc = 0.f;
  for (int i = i0; i < i1; ++i) {
    int g = batch[i];
    if (g != cur) {
      atomicAdd(&sums[cur * 64 + f], acc);
      acc = 0.f; cur = g;
    }
    acc += h[(size_t)i * 64 + f];
  }
  atomicAdd(&sums[cur * 64 + f], acc);
}

__global__ void k_pool2(const float* __restrict__ sums, const int* __restrict__ batch,
                        float* __restrict__ pooled, int n) {
  int g = blockIdx.x, f = threadIdx.x;
  int lo = 0, hi = n;
  while (lo < hi) { int m = (lo + hi) >> 1; if (batch[m] < g) lo = m + 1; else hi = m; }
  int start = lo;
  hi = n;
  while (lo < hi) { int m = (lo + hi) >> 1; if (batch[m] < g + 1) lo = m + 1; else hi = m; }
  float cnt = (float)(lo - start);
  pooled[g * 64 + f] = sums[g * 64 + f] / fmaxf(cnt, 1.f);
}

// ---------------- launch ----------------

extern "C" void kernel_launch(void* const* d_in, const int* in_sizes, int n_in,
                              void* d_out, int out_size, void* d_ws, size_t ws_size,
                              hipStream_t stream) {
  const float* x   = (const float*)d_in[0];
  const int* eidx  = (const int*)d_in[1];
  const int* batch = (const int*)d_in[2];
  const float* W1  = (const float*)d_in[3];
  const float* b1  = (const float*)d_in[4];
  const float* W2  = (const float*)d_in[5];
  const float* b2  = (const float*)d_in[6];
  const float* W3  = (const float*)d_in[7];
  const float* b3  = (const float*)d_in[8];
  float* out = (float*)d_out;

  const int n = in_sizes[0] / 7;       // 50000
  const int e = in_sizes[1] / 2;       // 800000
  const int G = out_size / 64 - n;     // 50
  const int m = e + n;                 // CSR entries incl self-loops

  // workspace carve-up (4B elements)
  float* wsf = (float*)d_ws;
  int*   wsi = (int*)d_ws;
  size_t off = 0;
  int*   deg    = wsi + off; off += n;
  float* dinv   = wsf + off; off += n;
  int*   rp     = wsi + off; off += (size_t)((n + 1 + 3) & ~3);
  int*   cursor = wsi + off; off += n;
  int*   psum   = wsi + off; off += 256;
  float* sums   = wsf + off; off += (size_t)G * 64;
  int2*  csr    = (int2*)(wsi + off); off += (size_t)2 * m;
  float* bufA   = wsf + off; off += (size_t)n * 128;
  float* bufB   = wsf + off; off += (size_t)n * 128;

  // bf16 gather tensors alias the fp32 buffers (dataflow strictly serialized):
  //   t2 (bf16 h1, [n,128]) lives in bufB; consumed by agg128 before gemm2 writes bufB.
  //   t3 (bf16 h2@W3, [n,64]) lives in bufA; written by gemm3 after gemm2 consumed bufA.
  unsigned short* t2 = (unsigned short*)bufB;
  unsigned short* t3 = (unsigned short*)bufA;

  const int* src = eidx;       // edge_index[0]
  const int* dst = eidx + e;   // edge_index[1]

  const int nb = (n + 255) / 256;

  // CSR build
  k_init_deg<<<nb, 256, 0, stream>>>(deg, n);
  k_count<<<(e + 255) / 256, 256, 0, stream>>>(dst, deg, e);
  k_dinv<<<nb, 256, 0, stream>>>(deg, dinv, n);
  k_scan1<<<nb, 256, 0, stream>>>(deg, rp, psum, n);
  k_scan2<<<1, 256, 0, stream>>>(psum, nb);
  k_scan3<<<nb, 256, 0, stream>>>(rp, cursor, psum, n, m);
  k_scatter<<<(m + 255) / 256, 256, 0, stream>>>(src, dst, dinv, cursor, csr, e, n);
  // zero pooled sums (harness doesn't re-poison between replays)
  k_zero<<<(G * 64 + 255) / 256, 256, 0, stream>>>(sums, G * 64);

  // layer 1: AGG(x) [n,7] then @W1 + b1, relu -> bf16 t2
  k_agg7<<<((size_t)n * 64 + 255) / 256, 256, 0, stream>>>(x, csr, rp, bufA, n);
  k_gemm1<<<(n + 1) / 2, 256, 0, stream>>>(bufA, W1, b1, t2, n);

  // layer 2: AGG(t2 bf16) -> bufA fp32, then @W2 + b2, relu -> bufB fp32
  k_agg128<<<((size_t)n * 32 + 255) / 256, 256, 0, stream>>>(t2, csr, rp, bufA, n);
  k_gemm2<<<(n + 31) / 32, 256, 0, stream>>>(bufA, W2, b2, bufB, n);

  // layer 3: h2 @ W3 -> bf16 t3, then AGG + b3 -> d_out
  k_gemm3<<<(n + 31) / 32, 256, 0, stream>>>(bufB, W3, t3, n);
  k_agg64b<<<((size_t)n * 16 + 255) / 256, 256, 0, stream>>>(t3, csr, rp, b3, out, n);

  // mean pool -> d_out tail (node-parallel + finalize)
  const int waves = (n + 15) / 16;
  k_pool1<<<(waves * 64 + 255) / 256, 256, 0, stream>>>(out, batch, sums, n);
  k_pool2<<<G, 64, 0, stream>>>(sums, batch, out + (size_t)n * 64, n);
}